// Round 1
// baseline (8383.492 us; speedup 1.0000x reference)
//
#include <hip/hip_runtime.h>
#include <hip/hip_bf16.h>

#define D_MODEL 1024
#define N_HEADS 16
#define DEPTH   64
#define D_FF    4096
#define BATCH   2
#define SEQ     2048
#define NTOK    (BATCH * SEQ)   // 4096
#define EPS     1e-5f

// ---------------------------------------------------------------------------
// Generic tiled f32 GEMM:  C[M,N] = A[M,K] @ W[K,N] + bias[N]  (optional ReLU)
// 64x64 tile, BK=16, 256 threads, 4x4 per thread. M%64==0, N%64==0, K%16==0.
// ---------------------------------------------------------------------------
__global__ __launch_bounds__(256) void gemm_bias_kernel(
    const float* __restrict__ A, const float* __restrict__ W,
    const float* __restrict__ bias, float* __restrict__ C,
    int M, int N, int K, int relu)
{
    __shared__ float As[16][64];   // [k][m] (transposed store)
    __shared__ float Bs[16][64];   // [k][n]

    const int tid = threadIdx.x;
    const int bm = blockIdx.y * 64;
    const int bn = blockIdx.x * 64;
    const int tx = tid & 15, ty = tid >> 4;

    // A-tile load: 64 rows x 16 k -> one float4 per thread
    const int arow = tid >> 2, ak4 = (tid & 3) << 2;
    // B-tile load: 16 k rows x 64 cols -> one float4 per thread
    const int brow = tid >> 4, bn4 = (tid & 15) << 2;

    const float* Aptr = A + (size_t)(bm + arow) * K + ak4;
    const float* Wptr = W + (size_t)brow * N + bn + bn4;

    float acc[4][4] = {};

    for (int kt = 0; kt < K; kt += 16) {
        float4 av = *(const float4*)(Aptr + kt);
        float4 bv = *(const float4*)(Wptr + (size_t)kt * N);
        As[ak4 + 0][arow] = av.x;
        As[ak4 + 1][arow] = av.y;
        As[ak4 + 2][arow] = av.z;
        As[ak4 + 3][arow] = av.w;
        *(float4*)&Bs[brow][bn4] = bv;
        __syncthreads();
#pragma unroll
        for (int k = 0; k < 16; ++k) {
            float4 a = *(const float4*)&As[k][ty << 2];
            float4 b = *(const float4*)&Bs[k][tx << 2];
            float ar[4] = {a.x, a.y, a.z, a.w};
            float br[4] = {b.x, b.y, b.z, b.w};
#pragma unroll
            for (int i = 0; i < 4; ++i)
#pragma unroll
                for (int j = 0; j < 4; ++j)
                    acc[i][j] = fmaf(ar[i], br[j], acc[i][j]);
        }
        __syncthreads();
    }

    float4 bb = *(const float4*)&bias[bn + (tx << 2)];
    float bbr[4] = {bb.x, bb.y, bb.z, bb.w};
#pragma unroll
    for (int i = 0; i < 4; ++i) {
        float4 o;
        float* op = &o.x;
#pragma unroll
        for (int j = 0; j < 4; ++j) {
            float v = acc[i][j] + bbr[j];
            if (relu) v = fmaxf(v, 0.f);
            op[j] = v;
        }
        *(float4*)&C[(size_t)(bm + (ty << 2) + i) * N + bn + (tx << 2)] = o;
    }
}

// ---------------------------------------------------------------------------
// Attention: one block (256 thr) per (b, h, q-row).
// Q,K,V,ctx layout: [B, S, D_MODEL] with head h occupying cols h*64..h*64+63.
// ---------------------------------------------------------------------------
__global__ __launch_bounds__(256) void attention_kernel(
    const float* __restrict__ Q, const float* __restrict__ K,
    const float* __restrict__ V, const int* __restrict__ mask,
    float* __restrict__ ctx)
{
    const int qi = blockIdx.x, h = blockIdx.y, b = blockIdx.z;
    const int tid = threadIdx.x;

    __shared__ float qv[64];
    __shared__ float p[SEQ];
    __shared__ float red[256];

    const size_t rowq = ((size_t)b * SEQ + qi) * D_MODEL + h * 64;
    if (tid < 64) qv[tid] = Q[rowq + tid];
    __syncthreads();

    // scores
    float lmax = -1e30f;
    for (int j = tid; j < SEQ; j += 256) {
        const float* kr = K + ((size_t)b * SEQ + j) * D_MODEL + h * 64;
        float acc = 0.f;
#pragma unroll
        for (int d = 0; d < 64; d += 4) {
            float4 kk = *(const float4*)&kr[d];
            acc += qv[d] * kk.x + qv[d + 1] * kk.y + qv[d + 2] * kk.z + qv[d + 3] * kk.w;
        }
        acc *= 0.125f;  // 1/sqrt(64)
        if (mask[b * SEQ + j] == 0) acc = -1e9f;
        p[j] = acc;
        lmax = fmaxf(lmax, acc);
    }
    // block max
#pragma unroll
    for (int o = 32; o > 0; o >>= 1) lmax = fmaxf(lmax, __shfl_down(lmax, o));
    if ((tid & 63) == 0) red[tid >> 6] = lmax;
    __syncthreads();
    const float m = fmaxf(fmaxf(red[0], red[1]), fmaxf(red[2], red[3]));
    __syncthreads();

    // exp + sum
    float lsum = 0.f;
    for (int j = tid; j < SEQ; j += 256) {
        float e = __expf(p[j] - m);
        p[j] = e;
        lsum += e;
    }
#pragma unroll
    for (int o = 32; o > 0; o >>= 1) lsum += __shfl_down(lsum, o);
    if ((tid & 63) == 0) red[tid >> 6] = lsum;
    __syncthreads();
    const float inv = 1.f / (red[0] + red[1] + red[2] + red[3]);
    __syncthreads();

    // p @ V : lane d in 0..63, 4 j-chunks of 512
    const int d = tid & 63, c = tid >> 6;
    float acc = 0.f;
    const float* vbase = V + (size_t)b * SEQ * D_MODEL + h * 64 + d;
    for (int j = c * 512; j < c * 512 + 512; ++j)
        acc += p[j] * vbase[(size_t)j * D_MODEL];
    red[tid] = acc;
    __syncthreads();
    if (tid < 64) {
        float s = (red[tid] + red[tid + 64] + red[tid + 128] + red[tid + 192]) * inv;
        ctx[rowq + tid] = s;
    }
}

// ---------------------------------------------------------------------------
// out = LayerNorm(X + Y) * g + b ; one block per token row of 1024
// ---------------------------------------------------------------------------
__global__ __launch_bounds__(256) void add_ln_kernel(
    const float* __restrict__ X, const float* __restrict__ Y,
    const float* __restrict__ g, const float* __restrict__ be,
    float* __restrict__ out)
{
    const int row = blockIdx.x, tid = threadIdx.x;
    __shared__ float red[4];

    const size_t base = (size_t)row * D_MODEL + tid * 4;
    float4 xv = *(const float4*)(X + base);
    float4 yv = *(const float4*)(Y + base);
    float4 s = {xv.x + yv.x, xv.y + yv.y, xv.z + yv.z, xv.w + yv.w};

    float ls = s.x + s.y + s.z + s.w;
#pragma unroll
    for (int o = 32; o > 0; o >>= 1) ls += __shfl_down(ls, o);
    if ((tid & 63) == 0) red[tid >> 6] = ls;
    __syncthreads();
    const float mu = (red[0] + red[1] + red[2] + red[3]) * (1.f / D_MODEL);
    __syncthreads();

    float d0 = s.x - mu, d1 = s.y - mu, d2 = s.z - mu, d3 = s.w - mu;
    float lv = d0 * d0 + d1 * d1 + d2 * d2 + d3 * d3;
#pragma unroll
    for (int o = 32; o > 0; o >>= 1) lv += __shfl_down(lv, o);
    if ((tid & 63) == 0) red[tid >> 6] = lv;
    __syncthreads();
    const float var = (red[0] + red[1] + red[2] + red[3]) * (1.f / D_MODEL);
    const float inv = rsqrtf(var + EPS);

    float4 gv = *(const float4*)(g + tid * 4);
    float4 bv = *(const float4*)(be + tid * 4);
    float4 o4 = {d0 * inv * gv.x + bv.x, d1 * inv * gv.y + bv.y,
                 d2 * inv * gv.z + bv.z, d3 * inv * gv.w + bv.w};
    *(float4*)(out + base) = o4;
}

// ---------------------------------------------------------------------------
extern "C" void kernel_launch(void* const* d_in, const int* in_sizes, int n_in,
                              void* d_out, int out_size, void* d_ws, size_t ws_size,
                              hipStream_t stream) {
    const float* x      = (const float*)d_in[0];
    const int*   mask   = (const int*)  d_in[1];
    const float* wq_w   = (const float*)d_in[2];
    const float* wq_b   = (const float*)d_in[3];
    const float* wk_w   = (const float*)d_in[4];
    const float* wk_b   = (const float*)d_in[5];
    const float* wv_w   = (const float*)d_in[6];
    const float* wv_b   = (const float*)d_in[7];
    const float* wo_w   = (const float*)d_in[8];
    const float* wo_b   = (const float*)d_in[9];
    const float* ffn_w1 = (const float*)d_in[10];
    const float* ffn_b1 = (const float*)d_in[11];
    const float* ffn_w2 = (const float*)d_in[12];
    const float* ffn_b2 = (const float*)d_in[13];
    const float* ln1_g  = (const float*)d_in[14];
    const float* ln1_b  = (const float*)d_in[15];
    const float* ln2_g  = (const float*)d_in[16];
    const float* ln2_b  = (const float*)d_in[17];
    float* out = (float*)d_out;

    float* ws = (float*)d_ws;
    const size_t TOKD = (size_t)NTOK * D_MODEL;   // 4,194,304
    float* Q    = ws;
    float* Kb   = Q  + TOKD;
    float* Vb   = Kb + TOKD;
    float* Ctx  = Vb + TOKD;
    float* Fh   = Ctx + TOKD;                     // NTOK * D_FF
    float* AttnOut = Q;    // Q dead after attention
    float* Out1    = Kb;   // K dead after attention
    float* FfnOut  = Ctx;  // ctx dead after wo-gemm

    dim3 blk(256);

    // QKV projections
    dim3 g_qkv(D_MODEL / 64, NTOK / 64);
    gemm_bias_kernel<<<g_qkv, blk, 0, stream>>>(x, wq_w, wq_b, Q,  NTOK, D_MODEL, D_MODEL, 0);
    gemm_bias_kernel<<<g_qkv, blk, 0, stream>>>(x, wk_w, wk_b, Kb, NTOK, D_MODEL, D_MODEL, 0);
    gemm_bias_kernel<<<g_qkv, blk, 0, stream>>>(x, wv_w, wv_b, Vb, NTOK, D_MODEL, D_MODEL, 0);

    // attention
    dim3 g_attn(SEQ, N_HEADS, BATCH);
    attention_kernel<<<g_attn, blk, 0, stream>>>(Q, Kb, Vb, mask, Ctx);

    // output projection
    gemm_bias_kernel<<<g_qkv, blk, 0, stream>>>(Ctx, wo_w, wo_b, AttnOut, NTOK, D_MODEL, D_MODEL, 0);

    // LN1
    add_ln_kernel<<<dim3(NTOK), blk, 0, stream>>>(x, AttnOut, ln1_g, ln1_b, Out1);

    // FFN
    dim3 g_f1(D_FF / 64, NTOK / 64);
    gemm_bias_kernel<<<g_f1, blk, 0, stream>>>(Out1, ffn_w1, ffn_b1, Fh, NTOK, D_FF, D_MODEL, 1);
    dim3 g_f2(D_MODEL / 64, NTOK / 64);
    gemm_bias_kernel<<<g_f2, blk, 0, stream>>>(Fh, ffn_w2, ffn_b2, FfnOut, NTOK, D_MODEL, D_FF, 0);

    // LN2 -> final output
    add_ln_kernel<<<dim3(NTOK), blk, 0, stream>>>(Out1, FfnOut, ln2_g, ln2_b, out);
}

// Round 2
// 811.866 us; speedup vs baseline: 10.3262x; 10.3262x over previous
//
#include <hip/hip_runtime.h>
#include <hip/hip_bf16.h>

#define D_MODEL 1024
#define N_HEADS 16
#define DEPTH   64
#define D_FF    4096
#define BATCH   2
#define SEQ     2048
#define NTOK    (BATCH * SEQ)   // 4096
#define EPS     1e-5f

typedef __attribute__((ext_vector_type(8))) short short8;
typedef __attribute__((ext_vector_type(4))) float f32x4;
typedef __attribute__((ext_vector_type(4))) unsigned short ushort4v;
typedef __attribute__((ext_vector_type(8))) unsigned short ushort8v;

__device__ __forceinline__ unsigned short f2bf(float f) {
    union { __hip_bfloat16 h; unsigned short u; } cv;
    cv.h = __float2bfloat16(f);   // RNE
    return cv.u;
}

__device__ __forceinline__ void gload16(const unsigned short* g, unsigned short* lds) {
    __builtin_amdgcn_global_load_lds(
        (const __attribute__((address_space(1))) void*)g,
        (__attribute__((address_space(3))) void*)lds, 16, 0, 0);
}

// ---------------------------------------------------------------------------
// cast f32 -> bf16 (8 elems/thread)
// ---------------------------------------------------------------------------
__global__ __launch_bounds__(256) void cast_bf16_kernel(
    const float* __restrict__ in, unsigned short* __restrict__ out, int n)
{
    int i = (blockIdx.x * 256 + threadIdx.x) * 8;
    if (i >= n) return;
    f32x4 a = *(const f32x4*)&in[i];
    f32x4 b = *(const f32x4*)&in[i + 4];
    ushort8v o;
    o[0] = f2bf(a[0]); o[1] = f2bf(a[1]); o[2] = f2bf(a[2]); o[3] = f2bf(a[3]);
    o[4] = f2bf(b[0]); o[5] = f2bf(b[1]); o[6] = f2bf(b[2]); o[7] = f2bf(b[3]);
    *(ushort8v*)&out[i] = o;
}

// ---------------------------------------------------------------------------
// transpose + cast: W[K][N] f32 -> WT[N][K] bf16 (64x64 tiles)
// ---------------------------------------------------------------------------
__global__ __launch_bounds__(256) void transpose_cast_kernel(
    const float* __restrict__ W, unsigned short* __restrict__ WT, int K, int N)
{
    __shared__ float t[64][65];
    const int bk = blockIdx.y * 64, bn = blockIdx.x * 64;
    const int c4 = threadIdx.x & 15, r0 = threadIdx.x >> 4;
#pragma unroll
    for (int i = 0; i < 4; ++i) {
        int k = r0 + i * 16;
        f32x4 v = *(const f32x4*)&W[(size_t)(bk + k) * N + bn + c4 * 4];
#pragma unroll
        for (int jj = 0; jj < 4; ++jj) t[k][c4 * 4 + jj] = v[jj];
    }
    __syncthreads();
#pragma unroll
    for (int i = 0; i < 4; ++i) {
        int n = r0 + i * 16;
        ushort4v o;
#pragma unroll
        for (int jj = 0; jj < 4; ++jj) o[jj] = f2bf(t[c4 * 4 + jj][n]);
        *(ushort4v*)&WT[(size_t)(bn + n) * K + bk + c4 * 4] = o;
    }
}

__global__ __launch_bounds__(256) void concat3_kernel(
    const float* __restrict__ a, const float* __restrict__ b,
    const float* __restrict__ c, float* __restrict__ o)
{
    int i = blockIdx.x * 256 + threadIdx.x;
    if (i < 1024) o[i] = a[i];
    else if (i < 2048) o[i] = b[i - 1024];
    else if (i < 3072) o[i] = c[i - 2048];
}

// ---------------------------------------------------------------------------
// bf16 MFMA GEMM (m97 structure): C[M][N] = A[M][K] @ BT[N][K]^T + bias
// 128x128 tile, BK=64, 256 thr = 4 waves (2x2), wave tile 64x64 (4x4 frags).
// ---------------------------------------------------------------------------
__global__ __launch_bounds__(256) void gemm_bt_kernel(
    const unsigned short* __restrict__ A, const unsigned short* __restrict__ BT,
    const float* __restrict__ bias, float* __restrict__ C,
    unsigned short* __restrict__ Cb,
    int M, int N, int K, int relu, int out_bf)
{
    __shared__ unsigned short As[128 * 64];
    __shared__ unsigned short Bs[128 * 64];
    const int tid = threadIdx.x;
    const int lane = tid & 63, wv = tid >> 6;
    const int wr = wv >> 1, wc = wv & 1;
    const int bm = blockIdx.y * 128, bn = blockIdx.x * 128;
    const int lr = lane & 15, lk = (lane >> 4) << 3;

    f32x4 acc[4][4] = {};

    for (int kt = 0; kt < K; kt += 64) {
#pragma unroll
        for (int c = 0; c < 4; ++c) {
            int e = c * 2048 + tid * 8;
            int row = e >> 6, k = e & 63;
            gload16(A  + (size_t)(bm + row) * K + kt + k, As + c * 2048 + wv * 512);
            gload16(BT + (size_t)(bn + row) * K + kt + k, Bs + c * 2048 + wv * 512);
        }
        __syncthreads();
#pragma unroll
        for (int kk = 0; kk < 2; ++kk) {
            short8 af[4], bfr[4];
#pragma unroll
            for (int i = 0; i < 4; ++i) {
                af[i]  = *(const short8*)&As[(wr * 64 + i * 16 + lr) * 64 + kk * 32 + lk];
                bfr[i] = *(const short8*)&Bs[(wc * 64 + i * 16 + lr) * 64 + kk * 32 + lk];
            }
#pragma unroll
            for (int i = 0; i < 4; ++i)
#pragma unroll
                for (int j = 0; j < 4; ++j)
                    acc[i][j] = __builtin_amdgcn_mfma_f32_16x16x32_bf16(
                        af[i], bfr[j], acc[i][j], 0, 0, 0);
        }
        __syncthreads();
    }

    const int r0 = bm + wr * 64, c0 = bn + wc * 64;
    const int rq = (lane >> 4) * 4;
#pragma unroll
    for (int i = 0; i < 4; ++i)
#pragma unroll
        for (int j = 0; j < 4; ++j) {
            int col = c0 + j * 16 + lr;
            float bv = bias[col];
#pragma unroll
            for (int r = 0; r < 4; ++r) {
                int row = r0 + i * 16 + rq + r;
                float v = acc[i][j][r] + bv;
                if (relu) v = fmaxf(v, 0.f);
                if (out_bf) Cb[(size_t)row * N + col] = f2bf(v);
                else        C [(size_t)row * N + col] = v;
            }
        }
}

// ---------------------------------------------------------------------------
// Tiled flash attention, f32. QKV packed [NTOK][3072] (Q|K|V per row).
// Block: 64 q-rows x head. Thread (qg,g): q rows qg*4..+3, strips g*4..+3.
// ---------------------------------------------------------------------------
__global__ __launch_bounds__(256, 3) void attn_kernel(
    const float* __restrict__ QKV, const int* __restrict__ mask,
    float* __restrict__ ctx)
{
    const int qt = blockIdx.x * 64;
    const int h  = blockIdx.y;
    const int b  = blockIdx.z;
    const int tid = threadIdx.x;
    const int qg = tid >> 4, g = tid & 15;
    const int LD = 3 * D_MODEL;

    __shared__ float Qs[64 * 68];
    __shared__ float Ks[64 * 68];   // re-used as P after QK
    __shared__ float Vs[64 * 68];
    __shared__ int   Msk[64];

    const float* Qg = QKV + (size_t)(b * SEQ) * LD + h * 64;
    const float* Kg = Qg + D_MODEL;
    const float* Vg = Qg + 2 * D_MODEL;

    {
        const int c4 = tid & 15, r0 = tid >> 4;
#pragma unroll
        for (int i = 0; i < 4; ++i) {
            int r = r0 + i * 16;
            *(f32x4*)&Qs[r * 68 + c4 * 4] = *(const f32x4*)&Qg[(size_t)(qt + r) * LD + c4 * 4];
        }
    }

    float m_[4] = {-1e30f, -1e30f, -1e30f, -1e30f};
    float l_[4] = {};
    f32x4 o_[4] = {};

    for (int kv0 = 0; kv0 < SEQ; kv0 += 64) {
        __syncthreads();   // prev iteration fully done before restage
        {
            const int c4 = tid & 15, r0 = tid >> 4;
#pragma unroll
            for (int i = 0; i < 4; ++i) {
                int r = r0 + i * 16;
                *(f32x4*)&Ks[r * 68 + c4 * 4] = *(const f32x4*)&Kg[(size_t)(kv0 + r) * LD + c4 * 4];
                *(f32x4*)&Vs[r * 68 + c4 * 4] = *(const f32x4*)&Vg[(size_t)(kv0 + r) * LD + c4 * 4];
            }
            if (tid < 64) Msk[tid] = mask[b * SEQ + kv0 + tid];
        }
        __syncthreads();

        // QK^T : s[i][j] = Q[qg*4+i] . K[g*4+j]
        float s[4][4] = {};
#pragma unroll
        for (int dd = 0; dd < 16; ++dd) {
            const int d4 = ((dd + g) & 15) * 4;   // bank-rotation
            f32x4 qv[4], kv[4];
#pragma unroll
            for (int i = 0; i < 4; ++i) qv[i] = *(const f32x4*)&Qs[(qg * 4 + i) * 68 + d4];
#pragma unroll
            for (int j = 0; j < 4; ++j) kv[j] = *(const f32x4*)&Ks[(g * 4 + j) * 68 + d4];
#pragma unroll
            for (int i = 0; i < 4; ++i)
#pragma unroll
                for (int j = 0; j < 4; ++j) {
                    s[i][j] = fmaf(qv[i][0], kv[j][0], s[i][j]);
                    s[i][j] = fmaf(qv[i][1], kv[j][1], s[i][j]);
                    s[i][j] = fmaf(qv[i][2], kv[j][2], s[i][j]);
                    s[i][j] = fmaf(qv[i][3], kv[j][3], s[i][j]);
                }
        }
        __syncthreads();   // all Ks reads done before P overwrite

        // online softmax; P goes into Ks space (own-wave rows only)
#pragma unroll
        for (int i = 0; i < 4; ++i) {
#pragma unroll
            for (int j = 0; j < 4; ++j) {
                float v = s[i][j] * 0.125f;
                v = (Msk[g * 4 + j] == 0) ? -1e9f : v;
                s[i][j] = v;
            }
            float rm = fmaxf(fmaxf(s[i][0], s[i][1]), fmaxf(s[i][2], s[i][3]));
#pragma unroll
            for (int off = 1; off < 16; off <<= 1) rm = fmaxf(rm, __shfl_xor(rm, off));
            float nm = fmaxf(m_[i], rm);
            float rs = 0.f;
#pragma unroll
            for (int j = 0; j < 4; ++j) { float e = __expf(s[i][j] - nm); s[i][j] = e; rs += e; }
#pragma unroll
            for (int off = 1; off < 16; off <<= 1) rs += __shfl_xor(rs, off);
            float sc = __expf(m_[i] - nm);
            l_[i] = l_[i] * sc + rs;
            m_[i] = nm;
            o_[i] *= sc;
            f32x4 pv = {s[i][0], s[i][1], s[i][2], s[i][3]};
            *(f32x4*)&Ks[(qg * 4 + i) * 68 + g * 4] = pv;
        }

        // PV : o[i][d-strip] += P[row qg*4+i] @ V
#pragma unroll
        for (int kv4 = 0; kv4 < 16; ++kv4) {
            f32x4 p4[4];
#pragma unroll
            for (int i = 0; i < 4; ++i) p4[i] = *(const f32x4*)&Ks[(qg * 4 + i) * 68 + kv4 * 4];
#pragma unroll
            for (int jj = 0; jj < 4; ++jj) {
                f32x4 v4 = *(const f32x4*)&Vs[(kv4 * 4 + jj) * 68 + g * 4];
#pragma unroll
                for (int i = 0; i < 4; ++i) o_[i] += p4[i][jj] * v4;
            }
        }
    }

#pragma unroll
    for (int i = 0; i < 4; ++i) {
        f32x4 ov = o_[i] * (1.f / l_[i]);
        *(f32x4*)&ctx[(size_t)(b * SEQ + qt + qg * 4 + i) * D_MODEL + h * 64 + g * 4] = ov;
    }
}

// ---------------------------------------------------------------------------
// out = LayerNorm(X + Y) * g + b ; one block per token row of 1024
// ---------------------------------------------------------------------------
__global__ __launch_bounds__(256) void add_ln_kernel(
    const float* __restrict__ X, const float* __restrict__ Y,
    const float* __restrict__ g, const float* __restrict__ be,
    float* __restrict__ out)
{
    const int row = blockIdx.x, tid = threadIdx.x;
    __shared__ float red[4];

    const size_t base = (size_t)row * D_MODEL + tid * 4;
    float4 xv = *(const float4*)(X + base);
    float4 yv = *(const float4*)(Y + base);
    float4 s = {xv.x + yv.x, xv.y + yv.y, xv.z + yv.z, xv.w + yv.w};

    float ls = s.x + s.y + s.z + s.w;
#pragma unroll
    for (int o = 32; o > 0; o >>= 1) ls += __shfl_down(ls, o);
    if ((tid & 63) == 0) red[tid >> 6] = ls;
    __syncthreads();
    const float mu = (red[0] + red[1] + red[2] + red[3]) * (1.f / D_MODEL);
    __syncthreads();

    float d0 = s.x - mu, d1 = s.y - mu, d2 = s.z - mu, d3 = s.w - mu;
    float lv = d0 * d0 + d1 * d1 + d2 * d2 + d3 * d3;
#pragma unroll
    for (int o = 32; o > 0; o >>= 1) lv += __shfl_down(lv, o);
    if ((tid & 63) == 0) red[tid >> 6] = lv;
    __syncthreads();
    const float var = (red[0] + red[1] + red[2] + red[3]) * (1.f / D_MODEL);
    const float inv = rsqrtf(var + EPS);

    float4 gv = *(const float4*)(g + tid * 4);
    float4 bv = *(const float4*)(be + tid * 4);
    float4 o4 = {d0 * inv * gv.x + bv.x, d1 * inv * gv.y + bv.y,
                 d2 * inv * gv.z + bv.z, d3 * inv * gv.w + bv.w};
    *(float4*)(out + base) = o4;
}

// ---------------------------------------------------------------------------
extern "C" void kernel_launch(void* const* d_in, const int* in_sizes, int n_in,
                              void* d_out, int out_size, void* d_ws, size_t ws_size,
                              hipStream_t stream) {
    const float* x      = (const float*)d_in[0];
    const int*   mask   = (const int*)  d_in[1];
    const float* wq_w   = (const float*)d_in[2];
    const float* wq_b   = (const float*)d_in[3];
    const float* wk_w   = (const float*)d_in[4];
    const float* wk_b   = (const float*)d_in[5];
    const float* wv_w   = (const float*)d_in[6];
    const float* wv_b   = (const float*)d_in[7];
    const float* wo_w   = (const float*)d_in[8];
    const float* wo_b   = (const float*)d_in[9];
    const float* ffn_w1 = (const float*)d_in[10];
    const float* ffn_b1 = (const float*)d_in[11];
    const float* ffn_w2 = (const float*)d_in[12];
    const float* ffn_b2 = (const float*)d_in[13];
    const float* ln1_g  = (const float*)d_in[14];
    const float* ln1_b  = (const float*)d_in[15];
    const float* ln2_g  = (const float*)d_in[16];
    const float* ln2_b  = (const float*)d_in[17];
    float* out = (float*)d_out;

    char* w = (char*)d_ws;
    const size_t MB = 1024 * 1024;
    float*          QKV     = (float*)(w);              // 48MB [4096][3072]
    float*          AttnOut = QKV;                      // alias (QKV dead after attn)
    float*          Out1    = (float*)(w + 16 * MB);    // alias in QKV region
    float*          Ctx     = (float*)(w + 48 * MB);    // 16MB; FfnOut alias
    unsigned short* actb    = (unsigned short*)(w + 64 * MB);   // 8MB
    unsigned short* fhb     = (unsigned short*)(w + 72 * MB);   // 32MB
    float*          biasqkv = (float*)fhb;              // alias (pre-ffn1 only)
    unsigned short* wqkvT   = (unsigned short*)(w + 104 * MB);  // 6MB
    unsigned short* woT     = (unsigned short*)(w + 110 * MB);  // 2MB
    unsigned short* w1T     = (unsigned short*)(w + 112 * MB);  // 8MB
    unsigned short* w2T     = (unsigned short*)(w + 120 * MB);  // 8MB

    dim3 blk(256);

    // weight prep (bf16 + transpose), bias concat
    transpose_cast_kernel<<<dim3(16, 16), blk, 0, stream>>>(wq_w, wqkvT,                1024, 1024);
    transpose_cast_kernel<<<dim3(16, 16), blk, 0, stream>>>(wk_w, wqkvT + 1024 * 1024,  1024, 1024);
    transpose_cast_kernel<<<dim3(16, 16), blk, 0, stream>>>(wv_w, wqkvT + 2048 * 1024,  1024, 1024);
    transpose_cast_kernel<<<dim3(16, 16), blk, 0, stream>>>(wo_w, woT, 1024, 1024);
    transpose_cast_kernel<<<dim3(64, 16), blk, 0, stream>>>(ffn_w1, w1T, 1024, 4096);
    transpose_cast_kernel<<<dim3(16, 64), blk, 0, stream>>>(ffn_w2, w2T, 4096, 1024);
    concat3_kernel<<<dim3(12), blk, 0, stream>>>(wq_b, wk_b, wv_b, biasqkv);

    // x -> bf16
    cast_bf16_kernel<<<dim3(2048), blk, 0, stream>>>(x, actb, NTOK * D_MODEL);

    // merged QKV projection: [4096][3072]
    gemm_bt_kernel<<<dim3(24, 32), blk, 0, stream>>>(actb, wqkvT, biasqkv, QKV, nullptr,
                                                     NTOK, 3072, 1024, 0, 0);
    // attention
    attn_kernel<<<dim3(SEQ / 64, N_HEADS, BATCH), blk, 0, stream>>>(QKV, mask, Ctx);

    // ctx -> bf16; output projection
    cast_bf16_kernel<<<dim3(2048), blk, 0, stream>>>(Ctx, actb, NTOK * D_MODEL);
    gemm_bt_kernel<<<dim3(8, 32), blk, 0, stream>>>(actb, woT, wo_b, AttnOut, nullptr,
                                                    NTOK, 1024, 1024, 0, 0);
    // LN1
    add_ln_kernel<<<dim3(NTOK), blk, 0, stream>>>(x, AttnOut, ln1_g, ln1_b, Out1);

    // FFN
    cast_bf16_kernel<<<dim3(2048), blk, 0, stream>>>(Out1, actb, NTOK * D_MODEL);
    gemm_bt_kernel<<<dim3(32, 32), blk, 0, stream>>>(actb, w1T, ffn_b1, nullptr, fhb,
                                                     NTOK, D_FF, 1024, 1, 1);
    gemm_bt_kernel<<<dim3(8, 32), blk, 0, stream>>>(fhb, w2T, ffn_b2, Ctx, nullptr,
                                                    NTOK, 1024, D_FF, 0, 0);
    // LN2 -> out
    add_ln_kernel<<<dim3(NTOK), blk, 0, stream>>>(Out1, Ctx, ln2_g, ln2_b, out);
}

// Round 3
// 346.940 us; speedup vs baseline: 24.1641x; 2.3401x over previous
//
#include <hip/hip_runtime.h>
#include <hip/hip_bf16.h>

#define D_MODEL 1024
#define N_HEADS 16
#define DEPTH   64
#define D_FF    4096
#define BATCH   2
#define SEQ     2048
#define NTOK    (BATCH * SEQ)   // 4096
#define EPS     1e-5f

typedef __attribute__((ext_vector_type(8))) short short8;
typedef __attribute__((ext_vector_type(4))) float f32x4;
typedef __attribute__((ext_vector_type(4))) unsigned short ushort4v;
typedef __attribute__((ext_vector_type(8))) unsigned short ushort8v;

__device__ __forceinline__ unsigned short f2bf(float f) {
    union { __hip_bfloat16 h; unsigned short u; } cv;
    cv.h = __float2bfloat16(f);   // RNE
    return cv.u;
}

__device__ __forceinline__ void gload16(const unsigned short* g, unsigned short* lds) {
    __builtin_amdgcn_global_load_lds(
        (const __attribute__((address_space(1))) void*)g,
        (__attribute__((address_space(3))) void*)lds, 16, 0, 0);
}

// ---------------------------------------------------------------------------
// cast f32 -> bf16 (8 elems/thread)
// ---------------------------------------------------------------------------
__global__ __launch_bounds__(256) void cast_bf16_kernel(
    const float* __restrict__ in, unsigned short* __restrict__ out, int n)
{
    int i = (blockIdx.x * 256 + threadIdx.x) * 8;
    if (i >= n) return;
    f32x4 a = *(const f32x4*)&in[i];
    f32x4 b = *(const f32x4*)&in[i + 4];
    ushort8v o;
    o[0] = f2bf(a[0]); o[1] = f2bf(a[1]); o[2] = f2bf(a[2]); o[3] = f2bf(a[3]);
    o[4] = f2bf(b[0]); o[5] = f2bf(b[1]); o[6] = f2bf(b[2]); o[7] = f2bf(b[3]);
    *(ushort8v*)&out[i] = o;
}

// ---------------------------------------------------------------------------
// transpose + cast: W[K][N] f32 -> WT[N][K] bf16 (64x64 tiles)
// ---------------------------------------------------------------------------
__global__ __launch_bounds__(256) void transpose_cast_kernel(
    const float* __restrict__ W, unsigned short* __restrict__ WT, int K, int N)
{
    __shared__ float t[64][65];
    const int bk = blockIdx.y * 64, bn = blockIdx.x * 64;
    const int c4 = threadIdx.x & 15, r0 = threadIdx.x >> 4;
#pragma unroll
    for (int i = 0; i < 4; ++i) {
        int k = r0 + i * 16;
        f32x4 v = *(const f32x4*)&W[(size_t)(bk + k) * N + bn + c4 * 4];
#pragma unroll
        for (int jj = 0; jj < 4; ++jj) t[k][c4 * 4 + jj] = v[jj];
    }
    __syncthreads();
#pragma unroll
    for (int i = 0; i < 4; ++i) {
        int n = r0 + i * 16;
        ushort4v o;
#pragma unroll
        for (int jj = 0; jj < 4; ++jj) o[jj] = f2bf(t[c4 * 4 + jj][n]);
        *(ushort4v*)&WT[(size_t)(bn + n) * K + bk + c4 * 4] = o;
    }
}

__global__ __launch_bounds__(256) void concat3_kernel(
    const float* __restrict__ a, const float* __restrict__ b,
    const float* __restrict__ c, float* __restrict__ o)
{
    int i = blockIdx.x * 256 + threadIdx.x;
    if (i < 1024) o[i] = a[i];
    else if (i < 2048) o[i] = b[i - 1024];
    else if (i < 3072) o[i] = c[i - 2048];
}

// ---------------------------------------------------------------------------
// V^T extraction: QKV bf16 [tok][3072] (V at col 2048+) -> Vt[bh][64][2048]
// ---------------------------------------------------------------------------
__global__ __launch_bounds__(256) void vtrans_kernel(
    const unsigned short* __restrict__ QKV, unsigned short* __restrict__ Vt)
{
    __shared__ unsigned short T[64][72];
    const int st = blockIdx.x * 64;
    const int h = blockIdx.y, b = blockIdx.z;
    const int tid = threadIdx.x;
    const size_t tok0 = (size_t)b * SEQ;
    const int LD = 3 * D_MODEL;
    const int r = tid >> 3, c8 = (tid & 7) * 8;
#pragma unroll
    for (int p = 0; p < 2; ++p) {
        int row = p * 32 + r;
        *(ushort8v*)&T[row][c8] =
            *(const ushort8v*)&QKV[(tok0 + st + row) * LD + 2048 + h * 64 + c8];
    }
    __syncthreads();
    const int bh = b * N_HEADS + h;
#pragma unroll
    for (int p = 0; p < 2; ++p) {
        int d = p * 32 + r;
        ushort8v o;
#pragma unroll
        for (int e = 0; e < 8; ++e) o[e] = T[c8 + e][d];
        *(ushort8v*)&Vt[((size_t)bh * 64 + d) * SEQ + st + c8] = o;
    }
}

// ---------------------------------------------------------------------------
// bf16 MFMA GEMM (m97 structure): C[M][N] = A[M][K] @ BT[N][K]^T + bias
// ---------------------------------------------------------------------------
__global__ __launch_bounds__(256) void gemm_bt_kernel(
    const unsigned short* __restrict__ A, const unsigned short* __restrict__ BT,
    const float* __restrict__ bias, float* __restrict__ C,
    unsigned short* __restrict__ Cb,
    int M, int N, int K, int relu, int out_bf)
{
    __shared__ unsigned short As[128 * 64];
    __shared__ unsigned short Bs[128 * 64];
    const int tid = threadIdx.x;
    const int lane = tid & 63, wv = tid >> 6;
    const int wr = wv >> 1, wc = wv & 1;
    const int bm = blockIdx.y * 128, bn = blockIdx.x * 128;
    const int lr = lane & 15, lk = (lane >> 4) << 3;

    f32x4 acc[4][4] = {};

    for (int kt = 0; kt < K; kt += 64) {
#pragma unroll
        for (int c = 0; c < 4; ++c) {
            int e = c * 2048 + tid * 8;
            int row = e >> 6, k = e & 63;
            gload16(A  + (size_t)(bm + row) * K + kt + k, As + c * 2048 + wv * 512);
            gload16(BT + (size_t)(bn + row) * K + kt + k, Bs + c * 2048 + wv * 512);
        }
        __syncthreads();
#pragma unroll
        for (int kk = 0; kk < 2; ++kk) {
            short8 af[4], bfr[4];
#pragma unroll
            for (int i = 0; i < 4; ++i) {
                af[i]  = *(const short8*)&As[(wr * 64 + i * 16 + lr) * 64 + kk * 32 + lk];
                bfr[i] = *(const short8*)&Bs[(wc * 64 + i * 16 + lr) * 64 + kk * 32 + lk];
            }
#pragma unroll
            for (int i = 0; i < 4; ++i)
#pragma unroll
                for (int j = 0; j < 4; ++j)
                    acc[i][j] = __builtin_amdgcn_mfma_f32_16x16x32_bf16(
                        af[i], bfr[j], acc[i][j], 0, 0, 0);
        }
        __syncthreads();
    }

    const int r0 = bm + wr * 64, c0 = bn + wc * 64;
    const int rq = (lane >> 4) * 4;
#pragma unroll
    for (int i = 0; i < 4; ++i)
#pragma unroll
        for (int j = 0; j < 4; ++j) {
            int col = c0 + j * 16 + lr;
            float bv = bias[col];
#pragma unroll
            for (int r = 0; r < 4; ++r) {
                int row = r0 + i * 16 + rq + r;
                float v = acc[i][j][r] + bv;
                if (relu) v = fmaxf(v, 0.f);
                if (out_bf) Cb[(size_t)row * N + col] = f2bf(v);
                else        C [(size_t)row * N + col] = v;
            }
        }
}

// ---------------------------------------------------------------------------
// MFMA flash attention. 4 waves x 32 q-rows (block = 128 q), KVBLK = 64.
// QKV bf16 packed [tok][3072]; Vt bf16 [bh][64][2048]; ctx out bf16 [tok][1024].
// Swapped QK^T: S^T tile via mfma(Kfrag, Qfrag) -> lane holds q = i*16+(lane&15).
// K/V staged via global_load_lds with pre-swizzled source (slot ^= row&7).
// ---------------------------------------------------------------------------
__global__ __launch_bounds__(256, 2) void attn_mfma_kernel(
    const unsigned short* __restrict__ QKV,
    const unsigned short* __restrict__ Vt,
    const int* __restrict__ mask,
    unsigned short* __restrict__ ctx)
{
    const int tid = threadIdx.x;
    const int lane = tid & 63, w = tid >> 6;
    const int lr = lane & 15, g = lane >> 4;   // g in 0..3
    const int qt = blockIdx.x * 128;
    const int h = blockIdx.y, b = blockIdx.z;
    const int bh = b * N_HEADS + h;
    const size_t tok0 = (size_t)b * SEQ;
    const int LD = 3 * D_MODEL;

    __shared__ unsigned short Ks[2][64 * 64];   // [kv][d], 16B-slot swizzled
    __shared__ unsigned short Vs[2][64 * 64];   // [d][kv], 16B-slot swizzled
    __shared__ unsigned short Ps[4][32 * 64];   // per-wave P [q][kv], swizzled
    __shared__ float Msk[2][64];

    // Q B-frags in registers: qf[i][kk]; q = i*16 + lr, d = kk*32 + g*8..+7
    short8 qf[2][2];
#pragma unroll
    for (int i = 0; i < 2; ++i)
#pragma unroll
        for (int kk = 0; kk < 2; ++kk)
            qf[i][kk] = *(const short8*)&QKV[(tok0 + qt + w * 32 + i * 16 + lr) * LD
                                             + h * 64 + kk * 32 + g * 8];

    const int rsub = w * 8 + (lane >> 3);
    const int slot = lane & 7;

    float m_[2] = {-1e30f, -1e30f}, l_[2] = {0.f, 0.f};
    f32x4 o_[2][4] = {};   // [i][dj], C rows q = i*16 + g*4 + reg

    // ---- prologue: stage tile 0 into buf 0
    {
#pragma unroll
        for (int p = 0; p < 2; ++p) {
            const int row = p * 32 + rsub;
            const int ss = slot ^ (row & 7);
            gload16(QKV + (tok0 + row) * LD + D_MODEL + h * 64 + ss * 8,
                    &Ks[0][(p * 32 + w * 8) * 64]);
            gload16(Vt + ((size_t)bh * 64 + row) * SEQ + ss * 8,
                    &Vs[0][(p * 32 + w * 8) * 64]);
        }
        if (tid < 64) Msk[0][tid] = mask[b * SEQ + tid] ? 0.f : -1e9f;
    }
    __syncthreads();

    const int NT = SEQ / 64;
    int buf = 0;
    for (int t = 0; t < NT; ++t) {
        // stage next tile into other buffer (async; drained by end-of-loop barrier)
        if (t + 1 < NT) {
            const int nb = buf ^ 1;
#pragma unroll
            for (int p = 0; p < 2; ++p) {
                const int row = p * 32 + rsub;
                const int ss = slot ^ (row & 7);
                gload16(QKV + (tok0 + (t + 1) * 64 + row) * LD + D_MODEL + h * 64 + ss * 8,
                        &Ks[nb][(p * 32 + w * 8) * 64]);
                gload16(Vt + ((size_t)bh * 64 + row) * SEQ + (t + 1) * 64 + ss * 8,
                        &Vs[nb][(p * 32 + w * 8) * 64]);
            }
            if (tid < 64) Msk[buf ^ 1][tid] = mask[b * SEQ + (t + 1) * 64 + tid] ? 0.f : -1e9f;
        }

        // ---- QK^T (swapped): sacc[i][j] rows = kv (tile j), cols = q (sub i)
        f32x4 sacc[2][4] = {};
#pragma unroll
        for (int j = 0; j < 4; ++j) {
            short8 kf0 = *(const short8*)&Ks[buf][(j * 16 + lr) * 64 + ((0 + g) ^ (lr & 7)) * 8];
            short8 kf1 = *(const short8*)&Ks[buf][(j * 16 + lr) * 64 + ((4 + g) ^ (lr & 7)) * 8];
#pragma unroll
            for (int i = 0; i < 2; ++i) {
                sacc[i][j] = __builtin_amdgcn_mfma_f32_16x16x32_bf16(kf0, qf[i][0], sacc[i][j], 0, 0, 0);
                sacc[i][j] = __builtin_amdgcn_mfma_f32_16x16x32_bf16(kf1, qf[i][1], sacc[i][j], 0, 0, 0);
            }
        }

        // mask bias per (j,r): kv = j*16 + g*4 + r
        float mb[4][4];
#pragma unroll
        for (int j = 0; j < 4; ++j)
#pragma unroll
            for (int r = 0; r < 4; ++r) mb[j][r] = Msk[buf][j * 16 + g * 4 + r];

        // ---- online softmax per q-sub i (lane's q = i*16 + lr)
#pragma unroll
        for (int i = 0; i < 2; ++i) {
            float v[4][4];
            float tm = -1e30f;
#pragma unroll
            for (int j = 0; j < 4; ++j)
#pragma unroll
                for (int r = 0; r < 4; ++r) {
                    float x = sacc[i][j][r] * 0.125f + mb[j][r];
                    v[j][r] = x;
                    tm = fmaxf(tm, x);
                }
            tm = fmaxf(tm, __shfl_xor(tm, 16));
            tm = fmaxf(tm, __shfl_xor(tm, 32));
            const float nm = fmaxf(m_[i], tm);
            const float sc = __expf(m_[i] - nm);
            m_[i] = nm;
            float rs = 0.f;
#pragma unroll
            for (int j = 0; j < 4; ++j) {
                ushort4v pw;
#pragma unroll
                for (int r = 0; r < 4; ++r) {
                    float e = __expf(v[j][r] - nm);
                    rs += e;
                    pw[r] = f2bf(e);
                }
                // P[q = i*16+lr][kv = j*16 + g*4 .. +3], 8B write, swizzled
                *(ushort4v*)((char*)&Ps[w][0] + (i * 16 + lr) * 128
                             + ((j * 32 + g * 8) ^ ((lr & 7) << 4))) = pw;
            }
            rs += __shfl_xor(rs, 16);
            rs += __shfl_xor(rs, 32);
            l_[i] = l_[i] * sc + rs;
            // rescale O rows (q = i*16 + g*4 + r needs sc from lane lr' = g*4+r)
#pragma unroll
            for (int r = 0; r < 4; ++r) {
                float s_r = __shfl(sc, g * 4 + r);
#pragma unroll
                for (int dj = 0; dj < 4; ++dj) o_[i][dj][r] *= s_r;
            }
        }

        // ---- PV: O[q][d] += P[q][kv] @ V[kv][d]
#pragma unroll
        for (int kk = 0; kk < 2; ++kk) {
            short8 pf[2];
#pragma unroll
            for (int i = 0; i < 2; ++i)
                pf[i] = *(const short8*)&Ps[w][(i * 16 + lr) * 64 + ((kk * 4 + g) ^ (lr & 7)) * 8];
#pragma unroll
            for (int dj = 0; dj < 4; ++dj) {
                short8 vf = *(const short8*)&Vs[buf][(dj * 16 + lr) * 64 + ((kk * 4 + g) ^ (lr & 7)) * 8];
#pragma unroll
                for (int i = 0; i < 2; ++i)
                    o_[i][dj] = __builtin_amdgcn_mfma_f32_16x16x32_bf16(pf[i], vf, o_[i][dj], 0, 0, 0);
            }
        }

        __syncthreads();   // drains gloads (vmcnt) + all LDS reads of buf
        buf ^= 1;
    }

    // ---- epilogue: O /= l, write bf16 ctx
#pragma unroll
    for (int i = 0; i < 2; ++i) {
        const float invl = 1.f / l_[i];   // for q = i*16 + lr
#pragma unroll
        for (int r = 0; r < 4; ++r) {
            const float inv_r = __shfl(invl, g * 4 + r);
            const size_t tok = tok0 + qt + w * 32 + i * 16 + g * 4 + r;
#pragma unroll
            for (int dj = 0; dj < 4; ++dj)
                ctx[tok * D_MODEL + h * 64 + dj * 16 + lr] = f2bf(o_[i][dj][r] * inv_r);
        }
    }
}

// ---------------------------------------------------------------------------
// out = LayerNorm(X + Y) * g + b ; optional bf16 copy
// ---------------------------------------------------------------------------
__global__ __launch_bounds__(256) void add_ln_kernel(
    const float* __restrict__ X, const float* __restrict__ Y,
    const float* __restrict__ g, const float* __restrict__ be,
    float* __restrict__ out, unsigned short* __restrict__ outb)
{
    const int row = blockIdx.x, tid = threadIdx.x;
    __shared__ float red[4];

    const size_t base = (size_t)row * D_MODEL + tid * 4;
    float4 xv = *(const float4*)(X + base);
    float4 yv = *(const float4*)(Y + base);
    float4 s = {xv.x + yv.x, xv.y + yv.y, xv.z + yv.z, xv.w + yv.w};

    float ls = s.x + s.y + s.z + s.w;
#pragma unroll
    for (int o = 32; o > 0; o >>= 1) ls += __shfl_down(ls, o);
    if ((tid & 63) == 0) red[tid >> 6] = ls;
    __syncthreads();
    const float mu = (red[0] + red[1] + red[2] + red[3]) * (1.f / D_MODEL);
    __syncthreads();

    float d0 = s.x - mu, d1 = s.y - mu, d2 = s.z - mu, d3 = s.w - mu;
    float lv = d0 * d0 + d1 * d1 + d2 * d2 + d3 * d3;
#pragma unroll
    for (int o = 32; o > 0; o >>= 1) lv += __shfl_down(lv, o);
    if ((tid & 63) == 0) red[tid >> 6] = lv;
    __syncthreads();
    const float var = (red[0] + red[1] + red[2] + red[3]) * (1.f / D_MODEL);
    const float inv = rsqrtf(var + EPS);

    float4 gv = *(const float4*)(g + tid * 4);
    float4 bv = *(const float4*)(be + tid * 4);
    float4 o4 = {d0 * inv * gv.x + bv.x, d1 * inv * gv.y + bv.y,
                 d2 * inv * gv.z + bv.z, d3 * inv * gv.w + bv.w};
    *(float4*)(out + base) = o4;
    if (outb) {
        ushort4v ob = {f2bf(o4.x), f2bf(o4.y), f2bf(o4.z), f2bf(o4.w)};
        *(ushort4v*)(outb + base) = ob;
    }
}

// ---------------------------------------------------------------------------
extern "C" void kernel_launch(void* const* d_in, const int* in_sizes, int n_in,
                              void* d_out, int out_size, void* d_ws, size_t ws_size,
                              hipStream_t stream) {
    const float* x      = (const float*)d_in[0];
    const int*   mask   = (const int*)  d_in[1];
    const float* wq_w   = (const float*)d_in[2];
    const float* wq_b   = (const float*)d_in[3];
    const float* wk_w   = (const float*)d_in[4];
    const float* wk_b   = (const float*)d_in[5];
    const float* wv_w   = (const float*)d_in[6];
    const float* wv_b   = (const float*)d_in[7];
    const float* wo_w   = (const float*)d_in[8];
    const float* wo_b   = (const float*)d_in[9];
    const float* ffn_w1 = (const float*)d_in[10];
    const float* ffn_b1 = (const float*)d_in[11];
    const float* ffn_w2 = (const float*)d_in[12];
    const float* ffn_b2 = (const float*)d_in[13];
    const float* ln1_g  = (const float*)d_in[14];
    const float* ln1_b  = (const float*)d_in[15];
    const float* ln2_g  = (const float*)d_in[16];
    const float* ln2_b  = (const float*)d_in[17];
    float* out = (float*)d_out;

    char* w = (char*)d_ws;
    const size_t MB = 1024 * 1024;
    // lifetimes: A=prep B=qkv C=vt D=attn E=wo F=ln1 G=ffn1 H=ffn2 I=ln2
    unsigned short* qkvb  = (unsigned short*)(w);             // 0-24    B..D
    unsigned short* vt    = (unsigned short*)(w + 24 * MB);   // 24-32   C..D
    unsigned short* ctxb  = (unsigned short*)(w + 32 * MB);   // 32-40   D..E
    unsigned short* actb  = (unsigned short*)(w + 40 * MB);   // 40-48   A..B
    unsigned short* wqkvT = (unsigned short*)(w + 48 * MB);   // 48-54   A..B
    float*          AttnOut = (float*)(w + 40 * MB);          // 40-56   E..F
    unsigned short* woT   = (unsigned short*)(w + 56 * MB);   // 56-58   A..E
    float*          biasqkv = (float*)(w + 58 * MB);          // 58      A..B
    float*          Out1  = (float*)(w + 56 * MB);            // 56-72   F..I
    unsigned short* out1b = (unsigned short*)(w + 72 * MB);   // 72-80   F..G
    unsigned short* fhb   = (unsigned short*)(w + 80 * MB);   // 80-112  G..H
    unsigned short* w2T   = (unsigned short*)(w + 112 * MB);  // 112-120 A..H
    unsigned short* w1T   = (unsigned short*)(w + 120 * MB);  // 120-128 A..G
    float*          FfnOut = (float*)(w);                     // 0-16    H..I

    dim3 blk(256);

    // --- A: weight prep
    transpose_cast_kernel<<<dim3(16, 16), blk, 0, stream>>>(wq_w, wqkvT,               1024, 1024);
    transpose_cast_kernel<<<dim3(16, 16), blk, 0, stream>>>(wk_w, wqkvT + 1024 * 1024, 1024, 1024);
    transpose_cast_kernel<<<dim3(16, 16), blk, 0, stream>>>(wv_w, wqkvT + 2048 * 1024, 1024, 1024);
    transpose_cast_kernel<<<dim3(16, 16), blk, 0, stream>>>(wo_w, woT, 1024, 1024);
    transpose_cast_kernel<<<dim3(64, 16), blk, 0, stream>>>(ffn_w1, w1T, 1024, 4096);
    transpose_cast_kernel<<<dim3(16, 64), blk, 0, stream>>>(ffn_w2, w2T, 4096, 1024);
    concat3_kernel<<<dim3(12), blk, 0, stream>>>(wq_b, wk_b, wv_b, biasqkv);
    cast_bf16_kernel<<<dim3(2048), blk, 0, stream>>>(x, actb, NTOK * D_MODEL);

    // --- B: merged QKV projection -> bf16 packed
    gemm_bt_kernel<<<dim3(24, 32), blk, 0, stream>>>(actb, wqkvT, biasqkv, nullptr, qkvb,
                                                     NTOK, 3072, 1024, 0, 1);
    // --- C: V transpose
    vtrans_kernel<<<dim3(SEQ / 64, N_HEADS, BATCH), blk, 0, stream>>>(qkvb, vt);

    // --- D: MFMA flash attention
    attn_mfma_kernel<<<dim3(SEQ / 128, N_HEADS, BATCH), blk, 0, stream>>>(qkvb, vt, mask, ctxb);

    // --- E: output projection (f32 out)
    gemm_bt_kernel<<<dim3(8, 32), blk, 0, stream>>>(ctxb, woT, wo_b, AttnOut, nullptr,
                                                    NTOK, 1024, 1024, 0, 0);
    // --- F: LN1 (f32 + bf16)
    add_ln_kernel<<<dim3(NTOK), blk, 0, stream>>>(x, AttnOut, ln1_g, ln1_b, Out1, out1b);

    // --- G/H: FFN
    gemm_bt_kernel<<<dim3(32, 32), blk, 0, stream>>>(out1b, w1T, ffn_b1, nullptr, fhb,
                                                     NTOK, D_FF, 1024, 1, 1);
    gemm_bt_kernel<<<dim3(8, 32), blk, 0, stream>>>(fhb, w2T, ffn_b2, FfnOut, nullptr,
                                                    NTOK, 1024, D_FF, 0, 0);
    // --- I: LN2 -> out
    add_ln_kernel<<<dim3(NTOK), blk, 0, stream>>>(Out1, FfnOut, ln2_g, ln2_b, out, nullptr);
}

// Round 4
// 312.659 us; speedup vs baseline: 26.8136x; 1.1096x over previous
//
#include <hip/hip_runtime.h>
#include <hip/hip_bf16.h>

#define D_MODEL 1024
#define N_HEADS 16
#define DEPTH   64
#define D_FF    4096
#define BATCH   2
#define SEQ     2048
#define NTOK    (BATCH * SEQ)   // 4096
#define EPS     1e-5f

typedef __attribute__((ext_vector_type(8))) short short8;
typedef __attribute__((ext_vector_type(4))) float f32x4;
typedef __attribute__((ext_vector_type(4))) unsigned short ushort4v;
typedef __attribute__((ext_vector_type(8))) unsigned short ushort8v;

__device__ __forceinline__ unsigned short f2bf(float f) {
    union { __hip_bfloat16 h; unsigned short u; } cv;
    cv.h = __float2bfloat16(f);   // RNE
    return cv.u;
}

__device__ __forceinline__ void gload16(const unsigned short* g, unsigned short* lds) {
    __builtin_amdgcn_global_load_lds(
        (const __attribute__((address_space(1))) void*)g,
        (__attribute__((address_space(3))) void*)lds, 16, 0, 0);
}

// ---------------------------------------------------------------------------
// cast f32 -> bf16 (8 elems/thread)
// ---------------------------------------------------------------------------
__global__ __launch_bounds__(256) void cast_bf16_kernel(
    const float* __restrict__ in, unsigned short* __restrict__ out, int n)
{
    int i = (blockIdx.x * 256 + threadIdx.x) * 8;
    if (i >= n) return;
    f32x4 a = *(const f32x4*)&in[i];
    f32x4 b = *(const f32x4*)&in[i + 4];
    ushort8v o;
    o[0] = f2bf(a[0]); o[1] = f2bf(a[1]); o[2] = f2bf(a[2]); o[3] = f2bf(a[3]);
    o[4] = f2bf(b[0]); o[5] = f2bf(b[1]); o[6] = f2bf(b[2]); o[7] = f2bf(b[3]);
    *(ushort8v*)&out[i] = o;
}

// ---------------------------------------------------------------------------
// transpose + cast: W[K][N] f32 -> WT[N][K] bf16 (64x64 tiles)
// ---------------------------------------------------------------------------
__global__ __launch_bounds__(256) void transpose_cast_kernel(
    const float* __restrict__ W, unsigned short* __restrict__ WT, int K, int N)
{
    __shared__ float t[64][65];
    const int bk = blockIdx.y * 64, bn = blockIdx.x * 64;
    const int c4 = threadIdx.x & 15, r0 = threadIdx.x >> 4;
#pragma unroll
    for (int i = 0; i < 4; ++i) {
        int k = r0 + i * 16;
        f32x4 v = *(const f32x4*)&W[(size_t)(bk + k) * N + bn + c4 * 4];
#pragma unroll
        for (int jj = 0; jj < 4; ++jj) t[k][c4 * 4 + jj] = v[jj];
    }
    __syncthreads();
#pragma unroll
    for (int i = 0; i < 4; ++i) {
        int n = r0 + i * 16;
        ushort4v o;
#pragma unroll
        for (int jj = 0; jj < 4; ++jj) o[jj] = f2bf(t[c4 * 4 + jj][n]);
        *(ushort4v*)&WT[(size_t)(bn + n) * K + bk + c4 * 4] = o;
    }
}

__global__ __launch_bounds__(256) void concat3_kernel(
    const float* __restrict__ a, const float* __restrict__ b,
    const float* __restrict__ c, float* __restrict__ o)
{
    int i = blockIdx.x * 256 + threadIdx.x;
    if (i < 1024) o[i] = a[i];
    else if (i < 2048) o[i] = b[i - 1024];
    else if (i < 3072) o[i] = c[i - 2048];
}

// ---------------------------------------------------------------------------
// V^T extraction: QKV bf16 [tok][3072] (V at col 2048+) -> Vt[bh][64][2048]
// ---------------------------------------------------------------------------
__global__ __launch_bounds__(256) void vtrans_kernel(
    const unsigned short* __restrict__ QKV, unsigned short* __restrict__ Vt)
{
    __shared__ unsigned short T[64][72];
    const int st = blockIdx.x * 64;
    const int h = blockIdx.y, b = blockIdx.z;
    const int tid = threadIdx.x;
    const size_t tok0 = (size_t)b * SEQ;
    const int LD = 3 * D_MODEL;
    const int r = tid >> 3, c8 = (tid & 7) * 8;
#pragma unroll
    for (int p = 0; p < 2; ++p) {
        int row = p * 32 + r;
        *(ushort8v*)&T[row][c8] =
            *(const ushort8v*)&QKV[(tok0 + st + row) * LD + 2048 + h * 64 + c8];
    }
    __syncthreads();
    const int bh = b * N_HEADS + h;
#pragma unroll
    for (int p = 0; p < 2; ++p) {
        int d = p * 32 + r;
        ushort8v o;
#pragma unroll
        for (int e = 0; e < 8; ++e) o[e] = T[c8 + e][d];
        *(ushort8v*)&Vt[((size_t)bh * 64 + d) * SEQ + st + c8] = o;
    }
}

// ---------------------------------------------------------------------------
// 256x256 pipelined bf16 MFMA GEMM. C[M][N] = A[M][K] @ BT[N][K]^T + bias.
// 512 thr = 8 waves (2 wr x 4 wc), wave tile 128x64. BK=64, 2 K-steps in
// flight (2x64KB LDS buffers). Per K-step: 4 phases, each = {ds_read frags,
// 1 half-tile gload_lds prefetch, barrier, 16 MFMA, barrier}; one counted
// vmcnt(4) per K-step (T3+T4). LDS XOR-swizzle slot^=row&7 on both sides
// (pre-swizzled global source + swizzled ds_read) (T2). Requires K >= 128.
// ---------------------------------------------------------------------------
__global__ __launch_bounds__(512, 2) void gemm256_kernel(
    const unsigned short* __restrict__ A, const unsigned short* __restrict__ BT,
    const float* __restrict__ bias, float* __restrict__ C,
    unsigned short* __restrict__ Cb,
    int M, int N, int K, int relu, int out_bf)
{
    __shared__ unsigned short As[2][256 * 64];
    __shared__ unsigned short Bs[2][256 * 64];
    const int tid = threadIdx.x;
    const int lane = tid & 63, w = tid >> 6;
    const int wr = w >> 2, wc = w & 3;
    const int lr = lane & 15, g = lane >> 4;

    // XCD-aware block swizzle (bijective when nwg % 8 == 0)
    const int nwg = gridDim.x;
    int wg = blockIdx.x;
    if ((nwg & 7) == 0) wg = (wg & 7) * (nwg >> 3) + (wg >> 3);
    const int gx = N >> 8;
    const int bm = (wg / gx) * 256, bn = (wg % gx) * 256;

    const int srow = (w << 3) + (lane >> 3);               // staging row (mod 64-chunk)
    const int scol = ((lane & 7) ^ (lane >> 3)) << 3;      // pre-swizzled source col
    const int ldst = (w << 9);                             // wave-uniform LDS elem base

    // stage one 128-row half-tile (2 gloads/thread) of operand P at k0
#define STG(P, Xs, bufi, hf, rb, k0)                                          \
    {                                                                         \
        gload16(P + (size_t)((rb) + (hf) * 128 + srow) * K + (k0) + scol,     \
                &Xs[bufi][(hf) * 8192 + ldst]);                               \
        gload16(P + (size_t)((rb) + (hf) * 128 + 64 + srow) * K + (k0) + scol,\
                &Xs[bufi][(hf) * 8192 + 4096 + ldst]);                        \
    }

    const int NS = K >> 6;
    f32x4 acc[8][4] = {};

    // ---- prologue: A(0),B(0) -> buf0 ; B(1) -> buf1
    STG(A,  As, 0, 0, bm, 0); STG(A,  As, 0, 1, bm, 0);
    STG(BT, Bs, 0, 0, bn, 0); STG(BT, Bs, 0, 1, bn, 0);
    if (NS > 1) { STG(BT, Bs, 1, 0, bn, 64); STG(BT, Bs, 1, 1, bn, 64); }
    asm volatile("s_waitcnt vmcnt(4)" ::: "memory");
    __builtin_amdgcn_s_barrier();
    asm volatile("" ::: "memory");

    int buf = 0;
    short8 af[4][2], b0[2][2], b1[2][2];
    for (int s = 0; s < NS; ++s) {
        const int kn1 = (s + 1) << 6, kn2 = (s + 2) << 6;

        // ---- phase 1: read A(mh0)+B(nh0); stage A(s+1) h0 -> buf^1
#pragma unroll
        for (int i = 0; i < 4; ++i)
#pragma unroll
            for (int kk = 0; kk < 2; ++kk)
                af[i][kk] = *(const short8*)&As[buf][(wr * 128 + i * 16 + lr) * 64
                                                    + (((kk * 4 + g) ^ (lr & 7)) << 3)];
#pragma unroll
        for (int j = 0; j < 2; ++j)
#pragma unroll
            for (int kk = 0; kk < 2; ++kk)
                b0[j][kk] = *(const short8*)&Bs[buf][(wc * 64 + j * 16 + lr) * 64
                                                    + (((kk * 4 + g) ^ (lr & 7)) << 3)];
        if (s + 1 < NS) STG(A, As, buf ^ 1, 0, bm, kn1);
        asm volatile("" ::: "memory");
        __builtin_amdgcn_s_barrier();
        asm volatile("" ::: "memory");
        __builtin_amdgcn_s_setprio(1);
#pragma unroll
        for (int i = 0; i < 4; ++i)
#pragma unroll
            for (int j = 0; j < 2; ++j) {
                acc[i][j] = __builtin_amdgcn_mfma_f32_16x16x32_bf16(af[i][0], b0[j][0], acc[i][j], 0, 0, 0);
                acc[i][j] = __builtin_amdgcn_mfma_f32_16x16x32_bf16(af[i][1], b0[j][1], acc[i][j], 0, 0, 0);
            }
        __builtin_amdgcn_s_setprio(0);
        asm volatile("" ::: "memory");
        __builtin_amdgcn_s_barrier();
        asm volatile("" ::: "memory");

        // ---- phase 2: read B(nh1); stage A(s+1) h1 -> buf^1
#pragma unroll
        for (int j = 0; j < 2; ++j)
#pragma unroll
            for (int kk = 0; kk < 2; ++kk)
                b1[j][kk] = *(const short8*)&Bs[buf][(wc * 64 + (j + 2) * 16 + lr) * 64
                                                    + (((kk * 4 + g) ^ (lr & 7)) << 3)];
        if (s + 1 < NS) STG(A, As, buf ^ 1, 1, bm, kn1);
        asm volatile("" ::: "memory");
        __builtin_amdgcn_s_barrier();
        asm volatile("" ::: "memory");
        __builtin_amdgcn_s_setprio(1);
#pragma unroll
        for (int i = 0; i < 4; ++i)
#pragma unroll
            for (int j = 0; j < 2; ++j) {
                acc[i][j + 2] = __builtin_amdgcn_mfma_f32_16x16x32_bf16(af[i][0], b1[j][0], acc[i][j + 2], 0, 0, 0);
                acc[i][j + 2] = __builtin_amdgcn_mfma_f32_16x16x32_bf16(af[i][1], b1[j][1], acc[i][j + 2], 0, 0, 0);
            }
        __builtin_amdgcn_s_setprio(0);
        asm volatile("" ::: "memory");
        __builtin_amdgcn_s_barrier();
        asm volatile("" ::: "memory");

        // ---- phase 3: read A(mh1); stage B(s+2) h0 -> buf (B dead after ph2)
#pragma unroll
        for (int i = 0; i < 4; ++i)
#pragma unroll
            for (int kk = 0; kk < 2; ++kk)
                af[i][kk] = *(const short8*)&As[buf][(wr * 128 + 64 + i * 16 + lr) * 64
                                                    + (((kk * 4 + g) ^ (lr & 7)) << 3)];
        if (s + 2 < NS) STG(BT, Bs, buf, 0, bn, kn2);
        asm volatile("" ::: "memory");
        __builtin_amdgcn_s_barrier();
        asm volatile("" ::: "memory");
        __builtin_amdgcn_s_setprio(1);
#pragma unroll
        for (int i = 0; i < 4; ++i)
#pragma unroll
            for (int j = 0; j < 2; ++j) {
                acc[i + 4][j] = __builtin_amdgcn_mfma_f32_16x16x32_bf16(af[i][0], b0[j][0], acc[i + 4][j], 0, 0, 0);
                acc[i + 4][j] = __builtin_amdgcn_mfma_f32_16x16x32_bf16(af[i][1], b0[j][1], acc[i + 4][j], 0, 0, 0);
            }
        __builtin_amdgcn_s_setprio(0);
        asm volatile("" ::: "memory");
        __builtin_amdgcn_s_barrier();
        asm volatile("" ::: "memory");

        // ---- phase 4: stage B(s+2) h1 -> buf; MFMA; vmcnt(4) + barrier
        if (s + 2 < NS) STG(BT, Bs, buf, 1, bn, kn2);
        asm volatile("" ::: "memory");
        __builtin_amdgcn_s_barrier();
        asm volatile("" ::: "memory");
        __builtin_amdgcn_s_setprio(1);
#pragma unroll
        for (int i = 0; i < 4; ++i)
#pragma unroll
            for (int j = 0; j < 2; ++j) {
                acc[i + 4][j + 2] = __builtin_amdgcn_mfma_f32_16x16x32_bf16(af[i][0], b1[j][0], acc[i + 4][j + 2], 0, 0, 0);
                acc[i + 4][j + 2] = __builtin_amdgcn_mfma_f32_16x16x32_bf16(af[i][1], b1[j][1], acc[i + 4][j + 2], 0, 0, 0);
            }
        __builtin_amdgcn_s_setprio(0);
        asm volatile("s_waitcnt vmcnt(4)" ::: "memory");
        __builtin_amdgcn_s_barrier();
        asm volatile("" ::: "memory");

        buf ^= 1;
    }
#undef STG

    // ---- epilogue
#pragma unroll
    for (int i = 0; i < 8; ++i)
#pragma unroll
        for (int j = 0; j < 4; ++j) {
            const int col = bn + wc * 64 + j * 16 + lr;
            const float bv = bias[col];
#pragma unroll
            for (int r = 0; r < 4; ++r) {
                const int row = bm + wr * 128 + i * 16 + g * 4 + r;
                float v = acc[i][j][r] + bv;
                if (relu) v = fmaxf(v, 0.f);
                if (out_bf) Cb[(size_t)row * N + col] = f2bf(v);
                else        C [(size_t)row * N + col] = v;
            }
        }
}

// ---------------------------------------------------------------------------
// bf16 MFMA GEMM (m97 structure), 128x128 tile: used for N=1024 GEMMs
// ---------------------------------------------------------------------------
__global__ __launch_bounds__(256) void gemm_bt_kernel(
    const unsigned short* __restrict__ A, const unsigned short* __restrict__ BT,
    const float* __restrict__ bias, float* __restrict__ C,
    unsigned short* __restrict__ Cb,
    int M, int N, int K, int relu, int out_bf)
{
    __shared__ unsigned short As[128 * 64];
    __shared__ unsigned short Bs[128 * 64];
    const int tid = threadIdx.x;
    const int lane = tid & 63, wv = tid >> 6;
    const int wr = wv >> 1, wc = wv & 1;
    const int bm = blockIdx.y * 128, bn = blockIdx.x * 128;
    const int lr = lane & 15, lk = (lane >> 4) << 3;

    f32x4 acc[4][4] = {};

    for (int kt = 0; kt < K; kt += 64) {
#pragma unroll
        for (int c = 0; c < 4; ++c) {
            int e = c * 2048 + tid * 8;
            int row = e >> 6, k = e & 63;
            gload16(A  + (size_t)(bm + row) * K + kt + k, As + c * 2048 + wv * 512);
            gload16(BT + (size_t)(bn + row) * K + kt + k, Bs + c * 2048 + wv * 512);
        }
        __syncthreads();
#pragma unroll
        for (int kk = 0; kk < 2; ++kk) {
            short8 af[4], bfr[4];
#pragma unroll
            for (int i = 0; i < 4; ++i) {
                af[i]  = *(const short8*)&As[(wr * 64 + i * 16 + lr) * 64 + kk * 32 + lk];
                bfr[i] = *(const short8*)&Bs[(wc * 64 + i * 16 + lr) * 64 + kk * 32 + lk];
            }
#pragma unroll
            for (int i = 0; i < 4; ++i)
#pragma unroll
                for (int j = 0; j < 4; ++j)
                    acc[i][j] = __builtin_amdgcn_mfma_f32_16x16x32_bf16(
                        af[i], bfr[j], acc[i][j], 0, 0, 0);
        }
        __syncthreads();
    }

    const int r0 = bm + wr * 64, c0 = bn + wc * 64;
    const int rq = (lane >> 4) * 4;
#pragma unroll
    for (int i = 0; i < 4; ++i)
#pragma unroll
        for (int j = 0; j < 4; ++j) {
            int col = c0 + j * 16 + lr;
            float bv = bias[col];
#pragma unroll
            for (int r = 0; r < 4; ++r) {
                int row = r0 + i * 16 + rq + r;
                float v = acc[i][j][r] + bv;
                if (relu) v = fmaxf(v, 0.f);
                if (out_bf) Cb[(size_t)row * N + col] = f2bf(v);
                else        C [(size_t)row * N + col] = v;
            }
        }
}

// ---------------------------------------------------------------------------
// MFMA flash attention. 4 waves x 32 q-rows (block = 128 q), KVBLK = 64.
// ---------------------------------------------------------------------------
__global__ __launch_bounds__(256, 2) void attn_mfma_kernel(
    const unsigned short* __restrict__ QKV,
    const unsigned short* __restrict__ Vt,
    const int* __restrict__ mask,
    unsigned short* __restrict__ ctx)
{
    const int tid = threadIdx.x;
    const int lane = tid & 63, w = tid >> 6;
    const int lr = lane & 15, g = lane >> 4;   // g in 0..3
    const int qt = blockIdx.x * 128;
    const int h = blockIdx.y, b = blockIdx.z;
    const int bh = b * N_HEADS + h;
    const size_t tok0 = (size_t)b * SEQ;
    const int LD = 3 * D_MODEL;

    __shared__ unsigned short Ks[2][64 * 64];   // [kv][d], 16B-slot swizzled
    __shared__ unsigned short Vs[2][64 * 64];   // [d][kv], 16B-slot swizzled
    __shared__ unsigned short Ps[4][32 * 64];   // per-wave P [q][kv], swizzled
    __shared__ float Msk[2][64];

    short8 qf[2][2];
#pragma unroll
    for (int i = 0; i < 2; ++i)
#pragma unroll
        for (int kk = 0; kk < 2; ++kk)
            qf[i][kk] = *(const short8*)&QKV[(tok0 + qt + w * 32 + i * 16 + lr) * LD
                                             + h * 64 + kk * 32 + g * 8];

    const int rsub = w * 8 + (lane >> 3);
    const int slot = lane & 7;

    float m_[2] = {-1e30f, -1e30f}, l_[2] = {0.f, 0.f};
    f32x4 o_[2][4] = {};

    {
#pragma unroll
        for (int p = 0; p < 2; ++p) {
            const int row = p * 32 + rsub;
            const int ss = slot ^ (row & 7);
            gload16(QKV + (tok0 + row) * LD + D_MODEL + h * 64 + ss * 8,
                    &Ks[0][(p * 32 + w * 8) * 64]);
            gload16(Vt + ((size_t)bh * 64 + row) * SEQ + ss * 8,
                    &Vs[0][(p * 32 + w * 8) * 64]);
        }
        if (tid < 64) Msk[0][tid] = mask[b * SEQ + tid] ? 0.f : -1e9f;
    }
    __syncthreads();

    const int NT = SEQ / 64;
    int buf = 0;
    for (int t = 0; t < NT; ++t) {
        if (t + 1 < NT) {
            const int nb = buf ^ 1;
#pragma unroll
            for (int p = 0; p < 2; ++p) {
                const int row = p * 32 + rsub;
                const int ss = slot ^ (row & 7);
                gload16(QKV + (tok0 + (t + 1) * 64 + row) * LD + D_MODEL + h * 64 + ss * 8,
                        &Ks[nb][(p * 32 + w * 8) * 64]);
                gload16(Vt + ((size_t)bh * 64 + row) * SEQ + (t + 1) * 64 + ss * 8,
                        &Vs[nb][(p * 32 + w * 8) * 64]);
            }
            if (tid < 64) Msk[buf ^ 1][tid] = mask[b * SEQ + (t + 1) * 64 + tid] ? 0.f : -1e9f;
        }

        f32x4 sacc[2][4] = {};
#pragma unroll
        for (int j = 0; j < 4; ++j) {
            short8 kf0 = *(const short8*)&Ks[buf][(j * 16 + lr) * 64 + ((0 + g) ^ (lr & 7)) * 8];
            short8 kf1 = *(const short8*)&Ks[buf][(j * 16 + lr) * 64 + ((4 + g) ^ (lr & 7)) * 8];
#pragma unroll
            for (int i = 0; i < 2; ++i) {
                sacc[i][j] = __builtin_amdgcn_mfma_f32_16x16x32_bf16(kf0, qf[i][0], sacc[i][j], 0, 0, 0);
                sacc[i][j] = __builtin_amdgcn_mfma_f32_16x16x32_bf16(kf1, qf[i][1], sacc[i][j], 0, 0, 0);
            }
        }

        float mb[4][4];
#pragma unroll
        for (int j = 0; j < 4; ++j)
#pragma unroll
            for (int r = 0; r < 4; ++r) mb[j][r] = Msk[buf][j * 16 + g * 4 + r];

#pragma unroll
        for (int i = 0; i < 2; ++i) {
            float v[4][4];
            float tm = -1e30f;
#pragma unroll
            for (int j = 0; j < 4; ++j)
#pragma unroll
                for (int r = 0; r < 4; ++r) {
                    float x = sacc[i][j][r] * 0.125f + mb[j][r];
                    v[j][r] = x;
                    tm = fmaxf(tm, x);
                }
            tm = fmaxf(tm, __shfl_xor(tm, 16));
            tm = fmaxf(tm, __shfl_xor(tm, 32));
            const float nm = fmaxf(m_[i], tm);
            const float sc = __expf(m_[i] - nm);
            m_[i] = nm;
            float rs = 0.f;
#pragma unroll
            for (int j = 0; j < 4; ++j) {
                ushort4v pw;
#pragma unroll
                for (int r = 0; r < 4; ++r) {
                    float e = __expf(v[j][r] - nm);
                    rs += e;
                    pw[r] = f2bf(e);
                }
                *(ushort4v*)((char*)&Ps[w][0] + (i * 16 + lr) * 128
                             + ((j * 32 + g * 8) ^ ((lr & 7) << 4))) = pw;
            }
            rs += __shfl_xor(rs, 16);
            rs += __shfl_xor(rs, 32);
            l_[i] = l_[i] * sc + rs;
#pragma unroll
            for (int r = 0; r < 4; ++r) {
                float s_r = __shfl(sc, g * 4 + r);
#pragma unroll
                for (int dj = 0; dj < 4; ++dj) o_[i][dj][r] *= s_r;
            }
        }

#pragma unroll
        for (int kk = 0; kk < 2; ++kk) {
            short8 pf[2];
#pragma unroll
            for (int i = 0; i < 2; ++i)
                pf[i] = *(const short8*)&Ps[w][(i * 16 + lr) * 64 + ((kk * 4 + g) ^ (lr & 7)) * 8];
#pragma unroll
            for (int dj = 0; dj < 4; ++dj) {
                short8 vf = *(const short8*)&Vs[buf][(dj * 16 + lr) * 64 + ((kk * 4 + g) ^ (lr & 7)) * 8];
#pragma unroll
                for (int i = 0; i < 2; ++i)
                    o_[i][dj] = __builtin_amdgcn_mfma_f32_16x16x32_bf16(pf[i], vf, o_[i][dj], 0, 0, 0);
            }
        }

        __syncthreads();
        buf ^= 1;
    }

#pragma unroll
    for (int i = 0; i < 2; ++i) {
        const float invl = 1.f / l_[i];
#pragma unroll
        for (int r = 0; r < 4; ++r) {
            const float inv_r = __shfl(invl, g * 4 + r);
            const size_t tok = tok0 + qt + w * 32 + i * 16 + g * 4 + r;
#pragma unroll
            for (int dj = 0; dj < 4; ++dj)
                ctx[tok * D_MODEL + h * 64 + dj * 16 + lr] = f2bf(o_[i][dj][r] * inv_r);
        }
    }
}

// ---------------------------------------------------------------------------
// out = LayerNorm(X + Y) * g + b ; optional bf16 copy
// ---------------------------------------------------------------------------
__global__ __launch_bounds__(256) void add_ln_kernel(
    const float* __restrict__ X, const float* __restrict__ Y,
    const float* __restrict__ g, const float* __restrict__ be,
    float* __restrict__ out, unsigned short* __restrict__ outb)
{
    const int row = blockIdx.x, tid = threadIdx.x;
    __shared__ float red[4];

    const size_t base = (size_t)row * D_MODEL + tid * 4;
    float4 xv = *(const float4*)(X + base);
    float4 yv = *(const float4*)(Y + base);
    float4 s = {xv.x + yv.x, xv.y + yv.y, xv.z + yv.z, xv.w + yv.w};

    float ls = s.x + s.y + s.z + s.w;
#pragma unroll
    for (int o = 32; o > 0; o >>= 1) ls += __shfl_down(ls, o);
    if ((tid & 63) == 0) red[tid >> 6] = ls;
    __syncthreads();
    const float mu = (red[0] + red[1] + red[2] + red[3]) * (1.f / D_MODEL);
    __syncthreads();

    float d0 = s.x - mu, d1 = s.y - mu, d2 = s.z - mu, d3 = s.w - mu;
    float lv = d0 * d0 + d1 * d1 + d2 * d2 + d3 * d3;
#pragma unroll
    for (int o = 32; o > 0; o >>= 1) lv += __shfl_down(lv, o);
    if ((tid & 63) == 0) red[tid >> 6] = lv;
    __syncthreads();
    const float var = (red[0] + red[1] + red[2] + red[3]) * (1.f / D_MODEL);
    const float inv = rsqrtf(var + EPS);

    float4 gv = *(const float4*)(g + tid * 4);
    float4 bv = *(const float4*)(be + tid * 4);
    float4 o4 = {d0 * inv * gv.x + bv.x, d1 * inv * gv.y + bv.y,
                 d2 * inv * gv.z + bv.z, d3 * inv * gv.w + bv.w};
    *(float4*)(out + base) = o4;
    if (outb) {
        ushort4v ob = {f2bf(o4.x), f2bf(o4.y), f2bf(o4.z), f2bf(o4.w)};
        *(ushort4v*)(outb + base) = ob;
    }
}

// ---------------------------------------------------------------------------
extern "C" void kernel_launch(void* const* d_in, const int* in_sizes, int n_in,
                              void* d_out, int out_size, void* d_ws, size_t ws_size,
                              hipStream_t stream) {
    const float* x      = (const float*)d_in[0];
    const int*   mask   = (const int*)  d_in[1];
    const float* wq_w   = (const float*)d_in[2];
    const float* wq_b   = (const float*)d_in[3];
    const float* wk_w   = (const float*)d_in[4];
    const float* wk_b   = (const float*)d_in[5];
    const float* wv_w   = (const float*)d_in[6];
    const float* wv_b   = (const float*)d_in[7];
    const float* wo_w   = (const float*)d_in[8];
    const float* wo_b   = (const float*)d_in[9];
    const float* ffn_w1 = (const float*)d_in[10];
    const float* ffn_b1 = (const float*)d_in[11];
    const float* ffn_w2 = (const float*)d_in[12];
    const float* ffn_b2 = (const float*)d_in[13];
    const float* ln1_g  = (const float*)d_in[14];
    const float* ln1_b  = (const float*)d_in[15];
    const float* ln2_g  = (const float*)d_in[16];
    const float* ln2_b  = (const float*)d_in[17];
    float* out = (float*)d_out;

    char* w = (char*)d_ws;
    const size_t MB = 1024 * 1024;
    unsigned short* qkvb  = (unsigned short*)(w);             // 0-24
    unsigned short* vt    = (unsigned short*)(w + 24 * MB);   // 24-32
    unsigned short* ctxb  = (unsigned short*)(w + 32 * MB);   // 32-40
    unsigned short* actb  = (unsigned short*)(w + 40 * MB);   // 40-48
    unsigned short* wqkvT = (unsigned short*)(w + 48 * MB);   // 48-54
    float*          AttnOut = (float*)(w + 40 * MB);          // 40-56
    unsigned short* woT   = (unsigned short*)(w + 56 * MB);   // 56-58
    float*          biasqkv = (float*)(w + 58 * MB);          // 58
    float*          Out1  = (float*)(w + 56 * MB);            // 56-72
    unsigned short* out1b = (unsigned short*)(w + 72 * MB);   // 72-80
    unsigned short* fhb   = (unsigned short*)(w + 80 * MB);   // 80-112
    unsigned short* w2T   = (unsigned short*)(w + 112 * MB);  // 112-120
    unsigned short* w1T   = (unsigned short*)(w + 120 * MB);  // 120-128
    float*          FfnOut = (float*)(w);                     // 0-16

    dim3 blk(256);

    // --- weight prep
    transpose_cast_kernel<<<dim3(16, 16), blk, 0, stream>>>(wq_w, wqkvT,               1024, 1024);
    transpose_cast_kernel<<<dim3(16, 16), blk, 0, stream>>>(wk_w, wqkvT + 1024 * 1024, 1024, 1024);
    transpose_cast_kernel<<<dim3(16, 16), blk, 0, stream>>>(wv_w, wqkvT + 2048 * 1024, 1024, 1024);
    transpose_cast_kernel<<<dim3(16, 16), blk, 0, stream>>>(wo_w, woT, 1024, 1024);
    transpose_cast_kernel<<<dim3(64, 16), blk, 0, stream>>>(ffn_w1, w1T, 1024, 4096);
    transpose_cast_kernel<<<dim3(16, 64), blk, 0, stream>>>(ffn_w2, w2T, 4096, 1024);
    concat3_kernel<<<dim3(12), blk, 0, stream>>>(wq_b, wk_b, wv_b, biasqkv);
    cast_bf16_kernel<<<dim3(2048), blk, 0, stream>>>(x, actb, NTOK * D_MODEL);

    // --- merged QKV projection -> bf16 packed (256x256 pipelined)
    gemm256_kernel<<<dim3(192), dim3(512), 0, stream>>>(actb, wqkvT, biasqkv, nullptr, qkvb,
                                                        NTOK, 3072, 1024, 0, 1);
    // --- V transpose
    vtrans_kernel<<<dim3(SEQ / 64, N_HEADS, BATCH), blk, 0, stream>>>(qkvb, vt);

    // --- MFMA flash attention
    attn_mfma_kernel<<<dim3(SEQ / 128, N_HEADS, BATCH), blk, 0, stream>>>(qkvb, vt, mask, ctxb);

    // --- output projection (f32 out)
    gemm_bt_kernel<<<dim3(8, 32), blk, 0, stream>>>(ctxb, woT, wo_b, AttnOut, nullptr,
                                                    NTOK, 1024, 1024, 0, 0);
    // --- LN1 (f32 + bf16)
    add_ln_kernel<<<dim3(NTOK), blk, 0, stream>>>(x, AttnOut, ln1_g, ln1_b, Out1, out1b);

    // --- FFN
    gemm256_kernel<<<dim3(256), dim3(512), 0, stream>>>(out1b, w1T, ffn_b1, nullptr, fhb,
                                                        NTOK, D_FF, 1024, 1, 1);
    gemm_bt_kernel<<<dim3(8, 32), blk, 0, stream>>>(fhb, w2T, ffn_b2, FfnOut, nullptr,
                                                    NTOK, 1024, D_FF, 0, 0);
    // --- LN2 -> out
    add_ln_kernel<<<dim3(NTOK), blk, 0, stream>>>(Out1, FfnOut, ln2_g, ln2_b, out, nullptr);
}

// Round 5
// 278.057 us; speedup vs baseline: 30.1502x; 1.1244x over previous
//
#include <hip/hip_runtime.h>
#include <hip/hip_bf16.h>

#define D_MODEL 1024
#define N_HEADS 16
#define DEPTH   64
#define D_FF    4096
#define BATCH   2
#define SEQ     2048
#define NTOK    (BATCH * SEQ)   // 4096
#define EPS     1e-5f

typedef __attribute__((ext_vector_type(8))) short short8;
typedef __attribute__((ext_vector_type(4))) float f32x4;
typedef __attribute__((ext_vector_type(4))) unsigned short ushort4v;
typedef __attribute__((ext_vector_type(8))) unsigned short ushort8v;

__device__ __forceinline__ unsigned short f2bf(float f) {
    union { __hip_bfloat16 h; unsigned short u; } cv;
    cv.h = __float2bfloat16(f);   // RNE
    return cv.u;
}

__device__ __forceinline__ void gload16(const unsigned short* g, unsigned short* lds) {
    __builtin_amdgcn_global_load_lds(
        (const __attribute__((address_space(1))) void*)g,
        (__attribute__((address_space(3))) void*)lds, 16, 0, 0);
}

// ---------------------------------------------------------------------------
// cast f32 -> bf16 (8 elems/thread)
// ---------------------------------------------------------------------------
__global__ __launch_bounds__(256) void cast_bf16_kernel(
    const float* __restrict__ in, unsigned short* __restrict__ out, int n)
{
    int i = (blockIdx.x * 256 + threadIdx.x) * 8;
    if (i >= n) return;
    f32x4 a = *(const f32x4*)&in[i];
    f32x4 b = *(const f32x4*)&in[i + 4];
    ushort8v o;
    o[0] = f2bf(a[0]); o[1] = f2bf(a[1]); o[2] = f2bf(a[2]); o[3] = f2bf(a[3]);
    o[4] = f2bf(b[0]); o[5] = f2bf(b[1]); o[6] = f2bf(b[2]); o[7] = f2bf(b[3]);
    *(ushort8v*)&out[i] = o;
}

// ---------------------------------------------------------------------------
// transpose + cast: W[K][N] f32 -> WT[N][K] bf16 (64x64 tiles)
// ---------------------------------------------------------------------------
__global__ __launch_bounds__(256) void transpose_cast_kernel(
    const float* __restrict__ W, unsigned short* __restrict__ WT, int K, int N)
{
    __shared__ float t[64][65];
    const int bk = blockIdx.y * 64, bn = blockIdx.x * 64;
    const int c4 = threadIdx.x & 15, r0 = threadIdx.x >> 4;
#pragma unroll
    for (int i = 0; i < 4; ++i) {
        int k = r0 + i * 16;
        f32x4 v = *(const f32x4*)&W[(size_t)(bk + k) * N + bn + c4 * 4];
#pragma unroll
        for (int jj = 0; jj < 4; ++jj) t[k][c4 * 4 + jj] = v[jj];
    }
    __syncthreads();
#pragma unroll
    for (int i = 0; i < 4; ++i) {
        int n = r0 + i * 16;
        ushort4v o;
#pragma unroll
        for (int jj = 0; jj < 4; ++jj) o[jj] = f2bf(t[c4 * 4 + jj][n]);
        *(ushort4v*)&WT[(size_t)(bn + n) * K + bk + c4 * 4] = o;
    }
}

__global__ __launch_bounds__(256) void concat3_kernel(
    const float* __restrict__ a, const float* __restrict__ b,
    const float* __restrict__ c, float* __restrict__ o)
{
    int i = blockIdx.x * 256 + threadIdx.x;
    if (i < 1024) o[i] = a[i];
    else if (i < 2048) o[i] = b[i - 1024];
    else if (i < 3072) o[i] = c[i - 2048];
}

// ---------------------------------------------------------------------------
// V^T extraction: QKV bf16 [tok][3072] (V at col 2048+) -> Vt[bh][64][2048]
// ---------------------------------------------------------------------------
__global__ __launch_bounds__(256) void vtrans_kernel(
    const unsigned short* __restrict__ QKV, unsigned short* __restrict__ Vt)
{
    __shared__ unsigned short T[64][72];
    const int st = blockIdx.x * 64;
    const int h = blockIdx.y, b = blockIdx.z;
    const int tid = threadIdx.x;
    const size_t tok0 = (size_t)b * SEQ;
    const int LD = 3 * D_MODEL;
    const int r = tid >> 3, c8 = (tid & 7) * 8;
#pragma unroll
    for (int p = 0; p < 2; ++p) {
        int row = p * 32 + r;
        *(ushort8v*)&T[row][c8] =
            *(const ushort8v*)&QKV[(tok0 + st + row) * LD + 2048 + h * 64 + c8];
    }
    __syncthreads();
    const int bh = b * N_HEADS + h;
#pragma unroll
    for (int p = 0; p < 2; ++p) {
        int d = p * 32 + r;
        ushort8v o;
#pragma unroll
        for (int e = 0; e < 8; ++e) o[e] = T[c8 + e][d];
        *(ushort8v*)&Vt[((size_t)bh * 64 + d) * SEQ + st + c8] = o;
    }
}

// ---------------------------------------------------------------------------
// 256x256 pipelined bf16 MFMA GEMM with optional split-K.
// C[M][N] = A[M][.] @ BT[N][.]^T (+ bias). lda = row stride of A/BT (full K);
// kLen = K handled per split; ksplit splits decoded from blockIdx.x.
// 512 thr = 8 waves (2 wr x 4 wc). 4 phases/K-step, counted vmcnt(4) (T3+T4),
// XOR-swizzled LDS (T2), setprio around MFMA (T5). Requires kLen >= 128.
// ---------------------------------------------------------------------------
__global__ __launch_bounds__(512, 2) void gemm256_kernel(
    const unsigned short* __restrict__ A, const unsigned short* __restrict__ BT,
    const float* __restrict__ bias, float* __restrict__ C,
    unsigned short* __restrict__ Cb,
    int M, int N, int lda, int kLen, int ksplit, int relu, int out_bf)
{
    __shared__ unsigned short As[2][256 * 64];
    __shared__ unsigned short Bs[2][256 * 64];
    const int tid = threadIdx.x;
    const int lane = tid & 63, w = tid >> 6;
    const int wr = w >> 2, wc = w & 3;
    const int lr = lane & 15, g = lane >> 4;

    // XCD-aware block swizzle (bijective when nwg % 8 == 0)
    const int nwg = gridDim.x;
    int wg = blockIdx.x;
    if ((nwg & 7) == 0) wg = (wg & 7) * (nwg >> 3) + (wg >> 3);
    if (ksplit > 1) {
        const int ntile = nwg / ksplit;
        const int split = wg / ntile;
        wg = wg % ntile;
        A  += (size_t)split * kLen;
        BT += (size_t)split * kLen;
        C  += (size_t)split * M * N;
    }
    const int gx = N >> 8;
    const int bm = (wg / gx) * 256, bn = (wg % gx) * 256;

    const int srow = (w << 3) + (lane >> 3);               // staging row (mod 64-chunk)
    const int scol = ((lane & 7) ^ (lane >> 3)) << 3;      // pre-swizzled source col
    const int ldst = (w << 9);                             // wave-uniform LDS elem base

#define STG(P, Xs, bufi, hf, rb, k0)                                            \
    {                                                                            \
        gload16(P + (size_t)((rb) + (hf) * 128 + srow) * lda + (k0) + scol,      \
                &Xs[bufi][(hf) * 8192 + ldst]);                                  \
        gload16(P + (size_t)((rb) + (hf) * 128 + 64 + srow) * lda + (k0) + scol, \
                &Xs[bufi][(hf) * 8192 + 4096 + ldst]);                           \
    }

    const int NS = kLen >> 6;
    f32x4 acc[8][4] = {};

    // ---- prologue: A(0),B(0) -> buf0 ; B(1) -> buf1
    STG(A,  As, 0, 0, bm, 0); STG(A,  As, 0, 1, bm, 0);
    STG(BT, Bs, 0, 0, bn, 0); STG(BT, Bs, 0, 1, bn, 0);
    if (NS > 1) { STG(BT, Bs, 1, 0, bn, 64); STG(BT, Bs, 1, 1, bn, 64); }
    asm volatile("s_waitcnt vmcnt(4)" ::: "memory");
    __builtin_amdgcn_s_barrier();
    asm volatile("" ::: "memory");

    int buf = 0;
    short8 af[4][2], b0[2][2], b1[2][2];
    for (int s = 0; s < NS; ++s) {
        const int kn1 = (s + 1) << 6, kn2 = (s + 2) << 6;

        // ---- phase 1: read A(mh0)+B(nh0); stage A(s+1) h0 -> buf^1
#pragma unroll
        for (int i = 0; i < 4; ++i)
#pragma unroll
            for (int kk = 0; kk < 2; ++kk)
                af[i][kk] = *(const short8*)&As[buf][(wr * 128 + i * 16 + lr) * 64
                                                    + (((kk * 4 + g) ^ (lr & 7)) << 3)];
#pragma unroll
        for (int j = 0; j < 2; ++j)
#pragma unroll
            for (int kk = 0; kk < 2; ++kk)
                b0[j][kk] = *(const short8*)&Bs[buf][(wc * 64 + j * 16 + lr) * 64
                                                    + (((kk * 4 + g) ^ (lr & 7)) << 3)];
        if (s + 1 < NS) STG(A, As, buf ^ 1, 0, bm, kn1);
        asm volatile("" ::: "memory");
        __builtin_amdgcn_s_barrier();
        asm volatile("" ::: "memory");
        __builtin_amdgcn_s_setprio(1);
#pragma unroll
        for (int i = 0; i < 4; ++i)
#pragma unroll
            for (int j = 0; j < 2; ++j) {
                acc[i][j] = __builtin_amdgcn_mfma_f32_16x16x32_bf16(af[i][0], b0[j][0], acc[i][j], 0, 0, 0);
                acc[i][j] = __builtin_amdgcn_mfma_f32_16x16x32_bf16(af[i][1], b0[j][1], acc[i][j], 0, 0, 0);
            }
        __builtin_amdgcn_s_setprio(0);
        asm volatile("" ::: "memory");
        __builtin_amdgcn_s_barrier();
        asm volatile("" ::: "memory");

        // ---- phase 2: read B(nh1); stage A(s+1) h1 -> buf^1
#pragma unroll
        for (int j = 0; j < 2; ++j)
#pragma unroll
            for (int kk = 0; kk < 2; ++kk)
                b1[j][kk] = *(const short8*)&Bs[buf][(wc * 64 + (j + 2) * 16 + lr) * 64
                                                    + (((kk * 4 + g) ^ (lr & 7)) << 3)];
        if (s + 1 < NS) STG(A, As, buf ^ 1, 1, bm, kn1);
        asm volatile("" ::: "memory");
        __builtin_amdgcn_s_barrier();
        asm volatile("" ::: "memory");
        __builtin_amdgcn_s_setprio(1);
#pragma unroll
        for (int i = 0; i < 4; ++i)
#pragma unroll
            for (int j = 0; j < 2; ++j) {
                acc[i][j + 2] = __builtin_amdgcn_mfma_f32_16x16x32_bf16(af[i][0], b1[j][0], acc[i][j + 2], 0, 0, 0);
                acc[i][j + 2] = __builtin_amdgcn_mfma_f32_16x16x32_bf16(af[i][1], b1[j][1], acc[i][j + 2], 0, 0, 0);
            }
        __builtin_amdgcn_s_setprio(0);
        asm volatile("" ::: "memory");
        __builtin_amdgcn_s_barrier();
        asm volatile("" ::: "memory");

        // ---- phase 3: read A(mh1); stage B(s+2) h0 -> buf (B dead after ph2)
#pragma unroll
        for (int i = 0; i < 4; ++i)
#pragma unroll
            for (int kk = 0; kk < 2; ++kk)
                af[i][kk] = *(const short8*)&As[buf][(wr * 128 + 64 + i * 16 + lr) * 64
                                                    + (((kk * 4 + g) ^ (lr & 7)) << 3)];
        if (s + 2 < NS) STG(BT, Bs, buf, 0, bn, kn2);
        asm volatile("" ::: "memory");
        __builtin_amdgcn_s_barrier();
        asm volatile("" ::: "memory");
        __builtin_amdgcn_s_setprio(1);
#pragma unroll
        for (int i = 0; i < 4; ++i)
#pragma unroll
            for (int j = 0; j < 2; ++j) {
                acc[i + 4][j] = __builtin_amdgcn_mfma_f32_16x16x32_bf16(af[i][0], b0[j][0], acc[i + 4][j], 0, 0, 0);
                acc[i + 4][j] = __builtin_amdgcn_mfma_f32_16x16x32_bf16(af[i][1], b0[j][1], acc[i + 4][j], 0, 0, 0);
            }
        __builtin_amdgcn_s_setprio(0);
        asm volatile("" ::: "memory");
        __builtin_amdgcn_s_barrier();
        asm volatile("" ::: "memory");

        // ---- phase 4: stage B(s+2) h1 -> buf; MFMA; vmcnt(4) + barrier
        if (s + 2 < NS) STG(BT, Bs, buf, 1, bn, kn2);
        asm volatile("" ::: "memory");
        __builtin_amdgcn_s_barrier();
        asm volatile("" ::: "memory");
        __builtin_amdgcn_s_setprio(1);
#pragma unroll
        for (int i = 0; i < 4; ++i)
#pragma unroll
            for (int j = 0; j < 2; ++j) {
                acc[i + 4][j + 2] = __builtin_amdgcn_mfma_f32_16x16x32_bf16(af[i][0], b1[j][0], acc[i + 4][j + 2], 0, 0, 0);
                acc[i + 4][j + 2] = __builtin_amdgcn_mfma_f32_16x16x32_bf16(af[i][1], b1[j][1], acc[i + 4][j + 2], 0, 0, 0);
            }
        __builtin_amdgcn_s_setprio(0);
        asm volatile("s_waitcnt vmcnt(4)" ::: "memory");
        __builtin_amdgcn_s_barrier();
        asm volatile("" ::: "memory");

        buf ^= 1;
    }
#undef STG

    // ---- epilogue
#pragma unroll
    for (int i = 0; i < 8; ++i)
#pragma unroll
        for (int j = 0; j < 4; ++j) {
            const int col = bn + wc * 64 + j * 16 + lr;
            const float bv = bias ? bias[col] : 0.f;
#pragma unroll
            for (int r = 0; r < 4; ++r) {
                const int row = bm + wr * 128 + i * 16 + g * 4 + r;
                float v = acc[i][j][r] + bv;
                if (relu) v = fmaxf(v, 0.f);
                if (out_bf) Cb[(size_t)row * N + col] = f2bf(v);
                else        C [(size_t)row * N + col] = v;
            }
        }
}

// ---------------------------------------------------------------------------
// bf16 MFMA GEMM (m97 structure), 128x128 tile, optional split-K via
// blockIdx.z: handles kLen of the contraction starting at blockIdx.z*kLen,
// writes f32 partials at C + z*M*N (bias may be nullptr).
// ---------------------------------------------------------------------------
__global__ __launch_bounds__(256) void gemm_bt_kernel(
    const unsigned short* __restrict__ A, const unsigned short* __restrict__ BT,
    const float* __restrict__ bias, float* __restrict__ C,
    unsigned short* __restrict__ Cb,
    int M, int N, int lda, int kLen, int relu, int out_bf)
{
    __shared__ unsigned short As[128 * 64];
    __shared__ unsigned short Bs[128 * 64];
    const int tid = threadIdx.x;
    const int lane = tid & 63, wv = tid >> 6;
    const int wr = wv >> 1, wc = wv & 1;
    const int bm = blockIdx.y * 128, bn = blockIdx.x * 128;
    const int kbase = blockIdx.z * kLen;
    const int lr = lane & 15, lk = (lane >> 4) << 3;

    C += (size_t)blockIdx.z * M * N;

    f32x4 acc[4][4] = {};

    for (int kt = 0; kt < kLen; kt += 64) {
#pragma unroll
        for (int c = 0; c < 4; ++c) {
            int e = c * 2048 + tid * 8;
            int row = e >> 6, k = e & 63;
            gload16(A  + (size_t)(bm + row) * lda + kbase + kt + k, As + c * 2048 + wv * 512);
            gload16(BT + (size_t)(bn + row) * lda + kbase + kt + k, Bs + c * 2048 + wv * 512);
        }
        __syncthreads();
#pragma unroll
        for (int kk = 0; kk < 2; ++kk) {
            short8 af[4], bfr[4];
#pragma unroll
            for (int i = 0; i < 4; ++i) {
                af[i]  = *(const short8*)&As[(wr * 64 + i * 16 + lr) * 64 + kk * 32 + lk];
                bfr[i] = *(const short8*)&Bs[(wc * 64 + i * 16 + lr) * 64 + kk * 32 + lk];
            }
#pragma unroll
            for (int i = 0; i < 4; ++i)
#pragma unroll
                for (int j = 0; j < 4; ++j)
                    acc[i][j] = __builtin_amdgcn_mfma_f32_16x16x32_bf16(
                        af[i], bfr[j], acc[i][j], 0, 0, 0);
        }
        __syncthreads();
    }

    const int r0 = bm + wr * 64, c0 = bn + wc * 64;
    const int rq = (lane >> 4) * 4;
#pragma unroll
    for (int i = 0; i < 4; ++i)
#pragma unroll
        for (int j = 0; j < 4; ++j) {
            int col = c0 + j * 16 + lr;
            float bv = bias ? bias[col] : 0.f;
#pragma unroll
            for (int r = 0; r < 4; ++r) {
                int row = r0 + i * 16 + rq + r;
                float v = acc[i][j][r] + bv;
                if (relu) v = fmaxf(v, 0.f);
                if (out_bf) Cb[(size_t)row * N + col] = f2bf(v);
                else        C [(size_t)row * N + col] = v;
            }
        }
}

// ---------------------------------------------------------------------------
// MFMA flash attention. 4 waves x 32 q-rows (block = 128 q), KVBLK = 64.
// ---------------------------------------------------------------------------
__global__ __launch_bounds__(256, 2) void attn_mfma_kernel(
    const unsigned short* __restrict__ QKV,
    const unsigned short* __restrict__ Vt,
    const int* __restrict__ mask,
    unsigned short* __restrict__ ctx)
{
    const int tid = threadIdx.x;
    const int lane = tid & 63, w = tid >> 6;
    const int lr = lane & 15, g = lane >> 4;   // g in 0..3
    const int qt = blockIdx.x * 128;
    const int h = blockIdx.y, b = blockIdx.z;
    const int bh = b * N_HEADS + h;
    const size_t tok0 = (size_t)b * SEQ;
    const int LD = 3 * D_MODEL;

    __shared__ unsigned short Ks[2][64 * 64];   // [kv][d], 16B-slot swizzled
    __shared__ unsigned short Vs[2][64 * 64];   // [d][kv], 16B-slot swizzled
    __shared__ unsigned short Ps[4][32 * 64];   // per-wave P [q][kv], swizzled
    __shared__ float Msk[2][64];

    short8 qf[2][2];
#pragma unroll
    for (int i = 0; i < 2; ++i)
#pragma unroll
        for (int kk = 0; kk < 2; ++kk)
            qf[i][kk] = *(const short8*)&QKV[(tok0 + qt + w * 32 + i * 16 + lr) * LD
                                             + h * 64 + kk * 32 + g * 8];

    const int rsub = w * 8 + (lane >> 3);
    const int slot = lane & 7;

    float m_[2] = {-1e30f, -1e30f}, l_[2] = {0.f, 0.f};
    f32x4 o_[2][4] = {};

    {
#pragma unroll
        for (int p = 0; p < 2; ++p) {
            const int row = p * 32 + rsub;
            const int ss = slot ^ (row & 7);
            gload16(QKV + (tok0 + row) * LD + D_MODEL + h * 64 + ss * 8,
                    &Ks[0][(p * 32 + w * 8) * 64]);
            gload16(Vt + ((size_t)bh * 64 + row) * SEQ + ss * 8,
                    &Vs[0][(p * 32 + w * 8) * 64]);
        }
        if (tid < 64) Msk[0][tid] = mask[b * SEQ + tid] ? 0.f : -1e9f;
    }
    __syncthreads();

    const int NT = SEQ / 64;
    int buf = 0;
    for (int t = 0; t < NT; ++t) {
        if (t + 1 < NT) {
            const int nb = buf ^ 1;
#pragma unroll
            for (int p = 0; p < 2; ++p) {
                const int row = p * 32 + rsub;
                const int ss = slot ^ (row & 7);
                gload16(QKV + (tok0 + (t + 1) * 64 + row) * LD + D_MODEL + h * 64 + ss * 8,
                        &Ks[nb][(p * 32 + w * 8) * 64]);
                gload16(Vt + ((size_t)bh * 64 + row) * SEQ + (t + 1) * 64 + ss * 8,
                        &Vs[nb][(p * 32 + w * 8) * 64]);
            }
            if (tid < 64) Msk[buf ^ 1][tid] = mask[b * SEQ + (t + 1) * 64 + tid] ? 0.f : -1e9f;
        }

        f32x4 sacc[2][4] = {};
#pragma unroll
        for (int j = 0; j < 4; ++j) {
            short8 kf0 = *(const short8*)&Ks[buf][(j * 16 + lr) * 64 + ((0 + g) ^ (lr & 7)) * 8];
            short8 kf1 = *(const short8*)&Ks[buf][(j * 16 + lr) * 64 + ((4 + g) ^ (lr & 7)) * 8];
#pragma unroll
            for (int i = 0; i < 2; ++i) {
                sacc[i][j] = __builtin_amdgcn_mfma_f32_16x16x32_bf16(kf0, qf[i][0], sacc[i][j], 0, 0, 0);
                sacc[i][j] = __builtin_amdgcn_mfma_f32_16x16x32_bf16(kf1, qf[i][1], sacc[i][j], 0, 0, 0);
            }
        }

        float mb[4][4];
#pragma unroll
        for (int j = 0; j < 4; ++j)
#pragma unroll
            for (int r = 0; r < 4; ++r) mb[j][r] = Msk[buf][j * 16 + g * 4 + r];

#pragma unroll
        for (int i = 0; i < 2; ++i) {
            float v[4][4];
            float tm = -1e30f;
#pragma unroll
            for (int j = 0; j < 4; ++j)
#pragma unroll
                for (int r = 0; r < 4; ++r) {
                    float x = sacc[i][j][r] * 0.125f + mb[j][r];
                    v[j][r] = x;
                    tm = fmaxf(tm, x);
                }
            tm = fmaxf(tm, __shfl_xor(tm, 16));
            tm = fmaxf(tm, __shfl_xor(tm, 32));
            const float nm = fmaxf(m_[i], tm);
            const float sc = __expf(m_[i] - nm);
            m_[i] = nm;
            float rs = 0.f;
#pragma unroll
            for (int j = 0; j < 4; ++j) {
                ushort4v pw;
#pragma unroll
                for (int r = 0; r < 4; ++r) {
                    float e = __expf(v[j][r] - nm);
                    rs += e;
                    pw[r] = f2bf(e);
                }
                *(ushort4v*)((char*)&Ps[w][0] + (i * 16 + lr) * 128
                             + ((j * 32 + g * 8) ^ ((lr & 7) << 4))) = pw;
            }
            rs += __shfl_xor(rs, 16);
            rs += __shfl_xor(rs, 32);
            l_[i] = l_[i] * sc + rs;
#pragma unroll
            for (int r = 0; r < 4; ++r) {
                float s_r = __shfl(sc, g * 4 + r);
#pragma unroll
                for (int dj = 0; dj < 4; ++dj) o_[i][dj][r] *= s_r;
            }
        }

#pragma unroll
        for (int kk = 0; kk < 2; ++kk) {
            short8 pf[2];
#pragma unroll
            for (int i = 0; i < 2; ++i)
                pf[i] = *(const short8*)&Ps[w][(i * 16 + lr) * 64 + ((kk * 4 + g) ^ (lr & 7)) * 8];
#pragma unroll
            for (int dj = 0; dj < 4; ++dj) {
                short8 vf = *(const short8*)&Vs[buf][(dj * 16 + lr) * 64 + ((kk * 4 + g) ^ (lr & 7)) * 8];
#pragma unroll
                for (int i = 0; i < 2; ++i)
                    o_[i][dj] = __builtin_amdgcn_mfma_f32_16x16x32_bf16(pf[i], vf, o_[i][dj], 0, 0, 0);
            }
        }

        __syncthreads();
        buf ^= 1;
    }

#pragma unroll
    for (int i = 0; i < 2; ++i) {
        const float invl = 1.f / l_[i];
#pragma unroll
        for (int r = 0; r < 4; ++r) {
            const float inv_r = __shfl(invl, g * 4 + r);
            const size_t tok = tok0 + qt + w * 32 + i * 16 + g * 4 + r;
#pragma unroll
            for (int dj = 0; dj < 4; ++dj)
                ctx[tok * D_MODEL + h * 64 + dj * 16 + lr] = f2bf(o_[i][dj][r] * inv_r);
        }
    }
}

// ---------------------------------------------------------------------------
// fused split-K reduce + residual + LayerNorm:
// out = LN( X + bias + sum_{s<nsplit} P[s] ) * g + b ; optional bf16 copy
// ---------------------------------------------------------------------------
__global__ __launch_bounds__(256) void reduce_ln_kernel(
    const float* __restrict__ P, int nsplit, const float* __restrict__ bias,
    const float* __restrict__ X, const float* __restrict__ g,
    const float* __restrict__ be, float* __restrict__ out,
    unsigned short* __restrict__ outb)
{
    const int row = blockIdx.x, tid = threadIdx.x;
    __shared__ float red[4];
    const size_t MN = (size_t)NTOK * D_MODEL;
    const size_t base = (size_t)row * D_MODEL + tid * 4;

    f32x4 s = *(const f32x4*)(X + base);
    f32x4 bb = *(const f32x4*)(bias + tid * 4);
    s += bb;
    for (int sp = 0; sp < nsplit; ++sp)
        s += *(const f32x4*)(P + sp * MN + base);

    float ls = s[0] + s[1] + s[2] + s[3];
#pragma unroll
    for (int o = 32; o > 0; o >>= 1) ls += __shfl_down(ls, o);
    if ((tid & 63) == 0) red[tid >> 6] = ls;
    __syncthreads();
    const float mu = (red[0] + red[1] + red[2] + red[3]) * (1.f / D_MODEL);
    __syncthreads();

    float d0 = s[0] - mu, d1 = s[1] - mu, d2 = s[2] - mu, d3 = s[3] - mu;
    float lv = d0 * d0 + d1 * d1 + d2 * d2 + d3 * d3;
#pragma unroll
    for (int o = 32; o > 0; o >>= 1) lv += __shfl_down(lv, o);
    if ((tid & 63) == 0) red[tid >> 6] = lv;
    __syncthreads();
    const float var = (red[0] + red[1] + red[2] + red[3]) * (1.f / D_MODEL);
    const float inv = rsqrtf(var + EPS);

    f32x4 gv = *(const f32x4*)(g + tid * 4);
    f32x4 bv = *(const f32x4*)(be + tid * 4);
    f32x4 o4 = {d0 * inv * gv[0] + bv[0], d1 * inv * gv[1] + bv[1],
                d2 * inv * gv[2] + bv[2], d3 * inv * gv[3] + bv[3]};
    *(f32x4*)(out + base) = o4;
    if (outb) {
        ushort4v ob = {f2bf(o4[0]), f2bf(o4[1]), f2bf(o4[2]), f2bf(o4[3])};
        *(ushort4v*)(outb + base) = ob;
    }
}

// ---------------------------------------------------------------------------
extern "C" void kernel_launch(void* const* d_in, const int* in_sizes, int n_in,
                              void* d_out, int out_size, void* d_ws, size_t ws_size,
                              hipStream_t stream) {
    const float* x      = (const float*)d_in[0];
    const int*   mask   = (const int*)  d_in[1];
    const float* wq_w   = (const float*)d_in[2];
    const float* wq_b   = (const float*)d_in[3];
    const float* wk_w   = (const float*)d_in[4];
    const float* wk_b   = (const float*)d_in[5];
    const float* wv_w   = (const float*)d_in[6];
    const float* wv_b   = (const float*)d_in[7];
    const float* wo_w   = (const float*)d_in[8];
    const float* wo_b   = (const float*)d_in[9];
    const float* ffn_w1 = (const float*)d_in[10];
    const float* ffn_b1 = (const float*)d_in[11];
    const float* ffn_w2 = (const float*)d_in[12];
    const float* ffn_b2 = (const float*)d_in[13];
    const float* ln1_g  = (const float*)d_in[14];
    const float* ln1_b  = (const float*)d_in[15];
    const float* ln2_g  = (const float*)d_in[16];
    const float* ln2_b  = (const float*)d_in[17];
    float* out = (float*)d_out;

    char* w = (char*)d_ws;
    const size_t MB = 1024 * 1024;
    // phases: A prep, B qkv, C vtrans, D attn, E wo, F ln1, G ffn1, H ffn2, I ln2
    unsigned short* actb    = (unsigned short*)(w);            // 0-8    A..B
    unsigned short* wqkvT   = (unsigned short*)(w + 8 * MB);   // 8-14   A..B
    float*          biasqkv = (float*)(w + 14 * MB);           // 14-16  A..B
    unsigned short* qkvb    = (unsigned short*)(w + 16 * MB);  // 16-40  B..D
    unsigned short* vt      = (unsigned short*)(w + 40 * MB);  // 40-48  C..D
    unsigned short* ctxb    = (unsigned short*)(w + 48 * MB);  // 48-56  D..E
    float*          woP     = (float*)(w);                     // 0-32   E..F (2 splits)
    unsigned short* out1b   = (unsigned short*)(w + 40 * MB);  // 40-48  F..G
    unsigned short* fhb     = (unsigned short*)(w + 64 * MB);  // 64-96  G..H
    unsigned short* w2T     = (unsigned short*)(w + 96 * MB);  // 96-104 A..H
    unsigned short* woT     = (unsigned short*)(w + 104 * MB); // 104-106 A..E
    float*          Out1    = (float*)(w + 104 * MB);          // 104-120 F..I
    unsigned short* w1T     = (unsigned short*)(w + 120 * MB); // 120-128 A..G
    float*          f2P     = (float*)(w);                     // 0-64   H..I (4 splits)

    dim3 blk(256);

    // --- A: weight prep
    transpose_cast_kernel<<<dim3(16, 16), blk, 0, stream>>>(wq_w, wqkvT,               1024, 1024);
    transpose_cast_kernel<<<dim3(16, 16), blk, 0, stream>>>(wk_w, wqkvT + 1024 * 1024, 1024, 1024);
    transpose_cast_kernel<<<dim3(16, 16), blk, 0, stream>>>(wv_w, wqkvT + 2048 * 1024, 1024, 1024);
    transpose_cast_kernel<<<dim3(16, 16), blk, 0, stream>>>(wo_w, woT, 1024, 1024);
    transpose_cast_kernel<<<dim3(64, 16), blk, 0, stream>>>(ffn_w1, w1T, 1024, 4096);
    transpose_cast_kernel<<<dim3(16, 64), blk, 0, stream>>>(ffn_w2, w2T, 4096, 1024);
    concat3_kernel<<<dim3(12), blk, 0, stream>>>(wq_b, wk_b, wv_b, biasqkv);
    cast_bf16_kernel<<<dim3(2048), blk, 0, stream>>>(x, actb, NTOK * D_MODEL);

    // --- B: merged QKV projection -> bf16 packed (256x256 pipelined)
    gemm256_kernel<<<dim3(192), dim3(512), 0, stream>>>(actb, wqkvT, biasqkv, nullptr, qkvb,
                                                        NTOK, 3072, 1024, 1024, 1, 0, 1);
    // --- C: V transpose
    vtrans_kernel<<<dim3(SEQ / 64, N_HEADS, BATCH), blk, 0, stream>>>(qkvb, vt);

    // --- D: MFMA flash attention
    attn_mfma_kernel<<<dim3(SEQ / 128, N_HEADS, BATCH), blk, 0, stream>>>(qkvb, vt, mask, ctxb);

    // --- E: output projection, split-K=2 -> f32 partials
    gemm_bt_kernel<<<dim3(8, 32, 2), blk, 0, stream>>>(ctxb, woT, nullptr, woP, nullptr,
                                                       NTOK, 1024, 1024, 512, 0, 0);
    // --- F: LN1 fused with wo-reduce (+ bf16 copy for ffn1)
    reduce_ln_kernel<<<dim3(NTOK), blk, 0, stream>>>(woP, 2, wo_b, x, ln1_g, ln1_b,
                                                     Out1, out1b);
    // --- G: FFN1 (256x256 pipelined)
    gemm256_kernel<<<dim3(256), dim3(512), 0, stream>>>(out1b, w1T, ffn_b1, nullptr, fhb,
                                                        NTOK, D_FF, 1024, 1024, 1, 1, 1);
    // --- H: FFN2, split-K=4 (256x256 pipelined) -> f32 partials
    gemm256_kernel<<<dim3(256), dim3(512), 0, stream>>>(fhb, w2T, nullptr, f2P, nullptr,
                                                        NTOK, 1024, 4096, 1024, 4, 0, 0);
    // --- I: LN2 fused with ffn2-reduce -> out
    reduce_ln_kernel<<<dim3(NTOK), blk, 0, stream>>>(f2P, 4, ffn_b2, Out1, ln2_g, ln2_b,
                                                     out, nullptr);
}